// Round 1
// baseline (376.887 us; speedup 1.0000x reference)
//
#include <hip/hip_runtime.h>
#include <hip/hip_bf16.h>

typedef __attribute__((ext_vector_type(8))) __bf16 bf16x8;
typedef __attribute__((ext_vector_type(4))) __bf16 bf16x4;
typedef __attribute__((ext_vector_type(4))) float f32x4;

#define B_    2
#define N_    2048
#define DIM_  1024
#define INNER_ 512
#define H_    8
#define DH_   64
#define ROWS_ (B_ * N_)       // 4096
#define QKVN_ (3 * INNER_)    // 1536

static __device__ inline f32x4 mfma16(bf16x8 a, bf16x8 b, f32x4 c) {
    return __builtin_amdgcn_mfma_f32_16x16x32_bf16(a, b, c, 0, 0, 0);
}

// ---------------- LayerNorm: x fp32 [4096][1024] -> xn bf16 ----------------
__global__ __launch_bounds__(256) void ln_kernel(const float* __restrict__ x,
                                                 const float* __restrict__ w,
                                                 const float* __restrict__ bb,
                                                 __bf16* __restrict__ xn) {
    int row = blockIdx.x;
    int tid = threadIdx.x;
    const float* xr = x + (size_t)row * DIM_;
    f32x4 xv = *reinterpret_cast<const f32x4*>(xr + tid * 4);
    float s  = xv.x + xv.y + xv.z + xv.w;
    float sq = xv.x * xv.x + xv.y * xv.y + xv.z * xv.z + xv.w * xv.w;
#pragma unroll
    for (int m = 1; m < 64; m <<= 1) {
        s  += __shfl_xor(s, m);
        sq += __shfl_xor(sq, m);
    }
    __shared__ float red[2][4];
    int wid = tid >> 6, lane = tid & 63;
    if (lane == 0) { red[0][wid] = s; red[1][wid] = sq; }
    __syncthreads();
    s  = red[0][0] + red[0][1] + red[0][2] + red[0][3];
    sq = red[1][0] + red[1][1] + red[1][2] + red[1][3];
    float mu   = s * (1.0f / DIM_);
    float var  = sq * (1.0f / DIM_) - mu * mu;
    float rstd = rsqrtf(var + 1e-5f);
    f32x4 wv = *reinterpret_cast<const f32x4*>(w  + tid * 4);
    f32x4 bv = *reinterpret_cast<const f32x4*>(bb + tid * 4);
    bf16x4 o;
#pragma unroll
    for (int j = 0; j < 4; ++j) o[j] = (__bf16)((xv[j] - mu) * rstd * wv[j] + bv[j]);
    *reinterpret_cast<bf16x4*>(xn + (size_t)row * DIM_ + tid * 4) = o;
}

// ------------- transpose+cast: in fp32 [K][N] -> out bf16 [N][K] -----------
__global__ void transpose_cast(const float* __restrict__ in, __bf16* __restrict__ out,
                               int K, int N) {
    int i = blockIdx.x * 256 + threadIdx.x;
    if (i >= K * N) return;
    int n = i / K;
    int k = i - n * K;
    out[i] = (__bf16)in[(size_t)k * N + n];
}

// --------- GEMM C[M][N] = A[M][K] * Bt[N][K]^T, bf16 in, OutT out ----------
// block = 4 waves; tile 64(M) x 64(N); each wave: 16(M) x 64(N)
template <typename OutT>
__global__ __launch_bounds__(256) void gemm_bt(const __bf16* __restrict__ A,
                                               const __bf16* __restrict__ Bt,
                                               OutT* __restrict__ C,
                                               int M, int N, int K) {
    int wid = threadIdx.x >> 6, lane = threadIdx.x & 63;
    int lr = lane & 15, lg = lane >> 4;
    int m0 = blockIdx.y * 64 + wid * 16;
    int n0 = blockIdx.x * 64;
    const __bf16* ap  = A  + (size_t)(m0 + lr) * K + 8 * lg;
    const __bf16* bp0 = Bt + (size_t)(n0 + lr) * K + 8 * lg;
    f32x4 acc[4];
#pragma unroll
    for (int c = 0; c < 4; ++c) acc[c] = f32x4{0.f, 0.f, 0.f, 0.f};
    for (int k = 0; k < K; k += 32) {
        bf16x8 a = *reinterpret_cast<const bf16x8*>(ap + k);
#pragma unroll
        for (int c = 0; c < 4; ++c) {
            bf16x8 bfr = *reinterpret_cast<const bf16x8*>(bp0 + (size_t)16 * c * K + k);
            acc[c] = mfma16(a, bfr, acc[c]);
        }
    }
#pragma unroll
    for (int c = 0; c < 4; ++c)
#pragma unroll
        for (int r = 0; r < 4; ++r)
            C[(size_t)(m0 + 4 * lg + r) * N + n0 + 16 * c + lr] = (OutT)acc[c][r];
}

// ---- split heads + l2norm(q)*8, l2norm(k); V transposed to [bh][64][n] ----
__global__ __launch_bounds__(256) void heads_kernel(const __bf16* __restrict__ qkv,
                                                    __bf16* __restrict__ Qh,
                                                    __bf16* __restrict__ Kh,
                                                    __bf16* __restrict__ Vt) {
    int task = blockIdx.x * 4 + (threadIdx.x >> 6);  // 0..32767 = row*8+h
    int lane = threadIdx.x & 63;
    int row = task >> 3, h = task & 7;
    int b = row >> 11, nn = row & 2047;
    const __bf16* base = qkv + (size_t)row * QKVN_ + h * DH_;
    float q = (float)base[lane];
    float k = (float)base[INNER_ + lane];
    float qs = q * q, ks = k * k;
#pragma unroll
    for (int m = 1; m < 64; m <<= 1) {
        qs += __shfl_xor(qs, m);
        ks += __shfl_xor(ks, m);
    }
    float qn = q * rsqrtf(qs + 1e-12f) * 8.0f;   // fold cosine-sim scale into q
    float kn = k * rsqrtf(ks + 1e-12f);
    size_t hb = (size_t)(b * H_ + h);
    Qh[hb * N_ * DH_ + (size_t)nn * DH_ + lane] = (__bf16)qn;
    Kh[hb * N_ * DH_ + (size_t)nn * DH_ + lane] = (__bf16)kn;
    Vt[hb * DH_ * N_ + (size_t)lane * N_ + nn]  = base[2 * INNER_ + lane];
}

// ------------------ causal flash attention, 1 wave / 16 q-rows -------------
__global__ __launch_bounds__(64) void attn_kernel(const __bf16* __restrict__ Qh,
                                                  const __bf16* __restrict__ Kh,
                                                  const __bf16* __restrict__ Vt,
                                                  __bf16* __restrict__ Ob) {
    int bh = blockIdx.y, qt = blockIdx.x;
    int lane = threadIdx.x;
    int lr = lane & 15, lg = lane >> 4;
    int qbase = qt * 16;
    const __bf16* Qp = Qh + (size_t)bh * N_ * DH_;
    const __bf16* Kp = Kh + (size_t)bh * N_ * DH_;
    const __bf16* Vp = Vt + (size_t)bh * DH_ * N_;
    bf16x8 qf0 = *reinterpret_cast<const bf16x8*>(Qp + (size_t)(qbase + lr) * DH_ + 8 * lg);
    bf16x8 qf1 = *reinterpret_cast<const bf16x8*>(Qp + (size_t)(qbase + lr) * DH_ + 32 + 8 * lg);
    f32x4 oacc[4];
#pragma unroll
    for (int c = 0; c < 4; ++c) oacc[c] = f32x4{0.f, 0.f, 0.f, 0.f};
    float m_r[4], l_r[4];
#pragma unroll
    for (int r = 0; r < 4; ++r) { m_r[r] = -1e30f; l_r[r] = 0.f; }
    __shared__ __align__(16) __bf16 pl[16][40];  // 16 rows x 32 cols, padded
    int jt_end = (qbase + 15) >> 5;
    for (int jt = 0; jt <= jt_end; ++jt) {
        int jb = jt << 5;
        f32x4 s[2];
#pragma unroll
        for (int ch = 0; ch < 2; ++ch) {
            const __bf16* kp = Kp + (size_t)(jb + 16 * ch + lr) * DH_ + 8 * lg;
            bf16x8 k0 = *reinterpret_cast<const bf16x8*>(kp);
            bf16x8 k1 = *reinterpret_cast<const bf16x8*>(kp + 32);
            f32x4 t = f32x4{0.f, 0.f, 0.f, 0.f};
            t = mfma16(qf0, k0, t);
            t = mfma16(qf1, k1, t);
            s[ch] = t;
        }
        // causal mask: D row = 4*lg + r (q), col = lr (k)
#pragma unroll
        for (int ch = 0; ch < 2; ++ch)
#pragma unroll
            for (int r = 0; r < 4; ++r) {
                int qi = qbase + 4 * lg + r;
                int j  = jb + 16 * ch + lr;
                if (j > qi) s[ch][r] = -1e30f;
            }
        float fs[4];
#pragma unroll
        for (int r = 0; r < 4; ++r) {
            float pm = fmaxf(s[0][r], s[1][r]);
#pragma unroll
            for (int msk = 1; msk < 16; msk <<= 1) pm = fmaxf(pm, __shfl_xor(pm, msk));
            float mn = fmaxf(m_r[r], pm);
            fs[r] = __expf(m_r[r] - mn);
            m_r[r] = mn;
        }
        f32x4 p[2];
#pragma unroll
        for (int ch = 0; ch < 2; ++ch)
#pragma unroll
            for (int r = 0; r < 4; ++r) p[ch][r] = __expf(s[ch][r] - m_r[r]);
#pragma unroll
        for (int r = 0; r < 4; ++r) {
            float rs = p[0][r] + p[1][r];
#pragma unroll
            for (int msk = 1; msk < 16; msk <<= 1) rs += __shfl_xor(rs, msk);
            l_r[r] = l_r[r] * fs[r] + rs;
        }
#pragma unroll
        for (int c = 0; c < 4; ++c)
#pragma unroll
            for (int r = 0; r < 4; ++r) oacc[c][r] *= fs[r];
        // transpose P through LDS to build PV A-fragment
#pragma unroll
        for (int ch = 0; ch < 2; ++ch)
#pragma unroll
            for (int r = 0; r < 4; ++r) pl[4 * lg + r][16 * ch + lr] = (__bf16)p[ch][r];
        __syncthreads();
        bf16x8 pf = *reinterpret_cast<const bf16x8*>(&pl[lr][8 * lg]);
#pragma unroll
        for (int dc = 0; dc < 4; ++dc) {
            bf16x8 vf = *reinterpret_cast<const bf16x8*>(Vp + (size_t)(16 * dc + lr) * N_ + jb + 8 * lg);
            oacc[dc] = mfma16(pf, vf, oacc[dc]);
        }
        __syncthreads();
    }
    int b = bh >> 3, h = bh & 7;
#pragma unroll
    for (int dc = 0; dc < 4; ++dc)
#pragma unroll
        for (int r = 0; r < 4; ++r) {
            size_t rowg = (size_t)b * N_ + qbase + 4 * lg + r;
            Ob[rowg * INNER_ + h * DH_ + 16 * dc + lr] = (__bf16)(oacc[dc][r] / l_r[r]);
        }
}

extern "C" void kernel_launch(void* const* d_in, const int* in_sizes, int n_in,
                              void* d_out, int out_size, void* d_ws, size_t ws_size,
                              hipStream_t stream) {
    const float* x    = (const float*)d_in[0];
    const float* lnw  = (const float*)d_in[1];
    const float* lnb  = (const float*)d_in[2];
    const float* wqkv = (const float*)d_in[3];
    const float* wout = (const float*)d_in[4];
    float* out = (float*)d_out;

    char* ws = (char*)d_ws;
    size_t off = 0;
    auto alloc = [&](size_t bytes) -> char* {
        char* p = ws + off;
        off += (bytes + 255) & ~(size_t)255;
        return p;
    };
    __bf16* xn    = (__bf16*)alloc((size_t)ROWS_ * DIM_ * 2);
    __bf16* wqkvT = (__bf16*)alloc((size_t)QKVN_ * DIM_ * 2);
    __bf16* woutT = (__bf16*)alloc((size_t)DIM_ * INNER_ * 2);
    __bf16* qkvb  = (__bf16*)alloc((size_t)ROWS_ * QKVN_ * 2);
    __bf16* Qhp   = (__bf16*)alloc((size_t)B_ * H_ * N_ * DH_ * 2);
    __bf16* Khp   = (__bf16*)alloc((size_t)B_ * H_ * N_ * DH_ * 2);
    __bf16* Vtp   = (__bf16*)alloc((size_t)B_ * H_ * DH_ * N_ * 2);
    __bf16* Obp   = (__bf16*)alloc((size_t)ROWS_ * INNER_ * 2);
    if (off > ws_size) return;  // workspace too small — fail visibly

    transpose_cast<<<(DIM_ * QKVN_ + 255) / 256, 256, 0, stream>>>(wqkv, wqkvT, DIM_, QKVN_);
    transpose_cast<<<(INNER_ * DIM_ + 255) / 256, 256, 0, stream>>>(wout, woutT, INNER_, DIM_);
    ln_kernel<<<ROWS_, 256, 0, stream>>>(x, lnw, lnb, xn);
    gemm_bt<__bf16><<<dim3(QKVN_ / 64, ROWS_ / 64), 256, 0, stream>>>(xn, wqkvT, qkvb, ROWS_, QKVN_, DIM_);
    heads_kernel<<<(ROWS_ * H_) / 4, 256, 0, stream>>>(qkvb, Qhp, Khp, Vtp);
    attn_kernel<<<dim3(N_ / 16, B_ * H_), 64, 0, stream>>>(Qhp, Khp, Vtp, Obp);
    gemm_bt<float><<<dim3(DIM_ / 64, ROWS_ / 64), 256, 0, stream>>>(Obp, woutT, out, ROWS_, DIM_, INNER_);
}

// Round 2
// 203.479 us; speedup vs baseline: 1.8522x; 1.8522x over previous
//
#include <hip/hip_runtime.h>
#include <hip/hip_bf16.h>

typedef __attribute__((ext_vector_type(8))) __bf16 bf16x8;
typedef __attribute__((ext_vector_type(4))) __bf16 bf16x4;
typedef __attribute__((ext_vector_type(4))) float f32x4;

#define B_     2
#define N_     2048
#define DIM_   1024
#define INNER_ 512
#define H_     8
#define DH_    64
#define ROWS_  (B_ * N_)      // 4096
#define QKVN_  (3 * INNER_)   // 1536

static __device__ __forceinline__ f32x4 mfma16(bf16x8 a, bf16x8 b, f32x4 c) {
    return __builtin_amdgcn_mfma_f32_16x16x32_bf16(a, b, c, 0, 0, 0);
}

static __device__ __forceinline__ void gld_lds16(const void* g, void* l) {
    __builtin_amdgcn_global_load_lds((const __attribute__((address_space(1))) void*)g,
                                     (__attribute__((address_space(3))) void*)l, 16, 0, 0);
}

// ---------------- LayerNorm: x fp32 [4096][1024] -> xn bf16 ----------------
__global__ __launch_bounds__(256) void ln_kernel(const float* __restrict__ x,
                                                 const float* __restrict__ w,
                                                 const float* __restrict__ bb,
                                                 __bf16* __restrict__ xn) {
    int row = blockIdx.x;
    int tid = threadIdx.x;
    const float* xr = x + (size_t)row * DIM_;
    f32x4 xv = *reinterpret_cast<const f32x4*>(xr + tid * 4);
    float s  = xv.x + xv.y + xv.z + xv.w;
    float sq = xv.x * xv.x + xv.y * xv.y + xv.z * xv.z + xv.w * xv.w;
#pragma unroll
    for (int m = 1; m < 64; m <<= 1) {
        s  += __shfl_xor(s, m);
        sq += __shfl_xor(sq, m);
    }
    __shared__ float red[2][4];
    int wid = tid >> 6, lane = tid & 63;
    if (lane == 0) { red[0][wid] = s; red[1][wid] = sq; }
    __syncthreads();
    s  = red[0][0] + red[0][1] + red[0][2] + red[0][3];
    sq = red[1][0] + red[1][1] + red[1][2] + red[1][3];
    float mu   = s * (1.0f / DIM_);
    float var  = sq * (1.0f / DIM_) - mu * mu;
    float rstd = rsqrtf(var + 1e-5f);
    f32x4 wv = *reinterpret_cast<const f32x4*>(w  + tid * 4);
    f32x4 bv = *reinterpret_cast<const f32x4*>(bb + tid * 4);
    bf16x4 o;
#pragma unroll
    for (int j = 0; j < 4; ++j) o[j] = (__bf16)((xv[j] - mu) * rstd * wv[j] + bv[j]);
    *reinterpret_cast<bf16x4*>(xn + (size_t)row * DIM_ + tid * 4) = o;
}

// ---- transpose+cast (coalesced): in fp32 [K][N] -> out bf16 [N][K] --------
__global__ __launch_bounds__(256) void transpose_cast(const float* __restrict__ in,
                                                      __bf16* __restrict__ out,
                                                      int K, int N) {
    __shared__ float t[64][65];
    int n0 = blockIdx.x * 64, k0 = blockIdx.y * 64;
    int w = threadIdx.x >> 6, lane = threadIdx.x & 63;
#pragma unroll
    for (int i = 0; i < 16; ++i) {
        int k = 16 * w + i;
        t[k][lane] = in[(size_t)(k0 + k) * N + n0 + lane];
    }
    __syncthreads();
#pragma unroll
    for (int i = 0; i < 16; ++i) {
        int n = 16 * w + i;
        out[(size_t)(n0 + n) * K + k0 + lane] = (__bf16)t[lane][n];
    }
}

// --------- GEMM C[M][N] = A[M][K] * Bt[N][K]^T, bf16 in, OutT out ----------
// m97 structure: 128x128 tile, BK=32, global_load_lds(16), 4 waves, 4x4 acc.
template <typename OutT>
__global__ __launch_bounds__(256) void gemm_bt(const __bf16* __restrict__ A,
                                               const __bf16* __restrict__ Bt,
                                               OutT* __restrict__ C,
                                               int M, int N, int K) {
    __shared__ __bf16 As[128 * 32];
    __shared__ __bf16 Bs[128 * 32];
    int tid = threadIdx.x;
    int w = tid >> 6, lane = tid & 63;
    int lr = lane & 15, lg = lane >> 4;
    int m0 = blockIdx.y * 128, n0 = blockIdx.x * 128;
    int wm = (w >> 1) * 64, wn = (w & 1) * 64;
    int srow = tid >> 2;   // 0..63
    int sc   = tid & 3;    // 16B chunk 0..3
    const __bf16* Ab = A  + (size_t)m0 * K;
    const __bf16* Bb = Bt + (size_t)n0 * K;
    f32x4 acc[4][4];
#pragma unroll
    for (int mi = 0; mi < 4; ++mi)
#pragma unroll
        for (int ci = 0; ci < 4; ++ci) acc[mi][ci] = f32x4{0.f, 0.f, 0.f, 0.f};
    for (int k0 = 0; k0 < K; k0 += 32) {
        __syncthreads();
#pragma unroll
        for (int q = 0; q < 2; ++q) {
            int row = q * 64 + srow;
            int cs = sc ^ (row & 3);   // pre-swizzled global source, linear LDS dest
            gld_lds16(Ab + (size_t)row * K + k0 + 8 * cs, &As[(size_t)row * 32 + sc * 8]);
            gld_lds16(Bb + (size_t)row * K + k0 + 8 * cs, &Bs[(size_t)row * 32 + sc * 8]);
        }
        __syncthreads();
        bf16x8 af[4], bfr[4];
#pragma unroll
        for (int mi = 0; mi < 4; ++mi) {
            int r = wm + 16 * mi + lr;
            af[mi] = *reinterpret_cast<const bf16x8*>(&As[r * 32 + 8 * (lg ^ (r & 3))]);
        }
#pragma unroll
        for (int ci = 0; ci < 4; ++ci) {
            int r = wn + 16 * ci + lr;
            bfr[ci] = *reinterpret_cast<const bf16x8*>(&Bs[r * 32 + 8 * (lg ^ (r & 3))]);
        }
#pragma unroll
        for (int mi = 0; mi < 4; ++mi)
#pragma unroll
            for (int ci = 0; ci < 4; ++ci)
                acc[mi][ci] = mfma16(af[mi], bfr[ci], acc[mi][ci]);
    }
#pragma unroll
    for (int mi = 0; mi < 4; ++mi)
#pragma unroll
        for (int ci = 0; ci < 4; ++ci)
#pragma unroll
            for (int r = 0; r < 4; ++r)
                C[(size_t)(m0 + wm + 16 * mi + 4 * lg + r) * N + n0 + wn + 16 * ci + lr] =
                    (OutT)acc[mi][ci][r];
}

// ---- split heads + l2norm(q)*8, l2norm(k); V transposed via LDS tile ------
__global__ __launch_bounds__(256) void heads_kernel(const __bf16* __restrict__ qkv,
                                                    __bf16* __restrict__ Qh,
                                                    __bf16* __restrict__ Kh,
                                                    __bf16* __restrict__ Vt) {
    __shared__ __bf16 vt[64][66];
    int bh = blockIdx.y;
    int b = bh >> 3, h = bh & 7;
    int r0 = blockIdx.x * 64;
    int w = threadIdx.x >> 6, lane = threadIdx.x & 63;
    size_t hb = (size_t)bh;
#pragma unroll 4
    for (int i = 0; i < 16; ++i) {
        int nloc = 16 * w + i;
        int n = r0 + nloc;
        const __bf16* base = qkv + ((size_t)(b * N_ + n)) * QKVN_ + h * DH_;
        float q = (float)base[lane];
        float k = (float)base[INNER_ + lane];
        float qs = q * q, ks = k * k;
#pragma unroll
        for (int m = 1; m < 64; m <<= 1) {
            qs += __shfl_xor(qs, m);
            ks += __shfl_xor(ks, m);
        }
        Qh[hb * N_ * DH_ + (size_t)n * DH_ + lane] = (__bf16)(q * rsqrtf(qs + 1e-12f) * 8.0f);
        Kh[hb * N_ * DH_ + (size_t)n * DH_ + lane] = (__bf16)(k * rsqrtf(ks + 1e-12f));
        vt[nloc][lane] = base[2 * INNER_ + lane];
    }
    __syncthreads();
#pragma unroll 4
    for (int i = 0; i < 16; ++i) {
        int d = 16 * w + i;
        Vt[hb * DH_ * N_ + (size_t)d * N_ + r0 + lane] = vt[lane][d];
    }
}

// ------- causal flash attention: 4 waves/block, QBLK=64, KVBLK=64 ----------
// K,V^T double-buffered in LDS (swizzled source + swizzled ds_read, T2/rule21)
__global__ __launch_bounds__(256) void attn_kernel(const __bf16* __restrict__ Qh,
                                                   const __bf16* __restrict__ Kh,
                                                   const __bf16* __restrict__ Vt,
                                                   __bf16* __restrict__ Ob) {
    __shared__ __bf16 Ks[2][64 * 64];
    __shared__ __bf16 Vs[2][64 * 64];
    __shared__ __bf16 pl[4][16][72];
    int bh = blockIdx.y;
    int qt = (gridDim.x - 1) - blockIdx.x;   // longest blocks dispatch first
    int tid = threadIdx.x;
    int w = tid >> 6, lane = tid & 63;
    int lr = lane & 15, lg = lane >> 4;
    int qb = qt * 64;
    int qrow = qb + 16 * w;                  // this wave's first q row
    const __bf16* Qp = Qh + (size_t)bh * N_ * DH_;
    const __bf16* Kp = Kh + (size_t)bh * N_ * DH_;
    const __bf16* Vp = Vt + (size_t)bh * DH_ * N_;
    bf16x8 qf0 = *reinterpret_cast<const bf16x8*>(Qp + (size_t)(qrow + lr) * DH_ + 8 * lg);
    bf16x8 qf1 = *reinterpret_cast<const bf16x8*>(Qp + (size_t)(qrow + lr) * DH_ + 32 + 8 * lg);
    f32x4 oacc[4];
#pragma unroll
    for (int c = 0; c < 4; ++c) oacc[c] = f32x4{0.f, 0.f, 0.f, 0.f};
    float m_r[4], l_r[4];
#pragma unroll
    for (int r = 0; r < 4; ++r) { m_r[r] = -1e30f; l_r[r] = 0.f; }
    int srow = tid >> 3;  // 0..31
    int sc   = tid & 7;   // 16B chunk 0..7

    auto stage = [&](int buf, int jb) {
#pragma unroll
        for (int q = 0; q < 2; ++q) {
            int row = q * 32 + srow;
            int cs = sc ^ (row & 7);
            gld_lds16(Kp + (size_t)(jb + row) * DH_ + 8 * cs,
                      &Ks[buf][(size_t)row * 64 + sc * 8]);
            gld_lds16(Vp + (size_t)row * N_ + jb + 8 * cs,
                      &Vs[buf][(size_t)row * 64 + sc * 8]);
        }
    };

    int jt_end = qt;
    stage(0, 0);
    __syncthreads();
    int cur = 0;
    for (int jt = 0; jt <= jt_end; ++jt) {
        int jb = jt * 64;
        if (jt < jt_end) stage(cur ^ 1, jb + 64);   // overlap with compute
        const __bf16* ks = &Ks[cur][0];
        const __bf16* vs = &Vs[cur][0];
        f32x4 s[4];
#pragma unroll
        for (int ch = 0; ch < 4; ++ch) {
            int row = 16 * ch + lr;
            bf16x8 k0 = *reinterpret_cast<const bf16x8*>(&ks[row * 64 + 8 * (lg ^ (row & 7))]);
            bf16x8 k1 = *reinterpret_cast<const bf16x8*>(&ks[row * 64 + 8 * ((4 + lg) ^ (row & 7))]);
            f32x4 t = f32x4{0.f, 0.f, 0.f, 0.f};
            t = mfma16(qf0, k0, t);
            t = mfma16(qf1, k1, t);
            s[ch] = t;
        }
        if (jb + 63 > qrow) {   // wave-uniform: only trailing tiles need masking
#pragma unroll
            for (int ch = 0; ch < 4; ++ch)
#pragma unroll
                for (int r = 0; r < 4; ++r) {
                    int qi = qrow + 4 * lg + r;
                    int j  = jb + 16 * ch + lr;
                    if (j > qi) s[ch][r] = -1e30f;
                }
        }
        float fs[4];
#pragma unroll
        for (int r = 0; r < 4; ++r) {
            float pm = fmaxf(fmaxf(s[0][r], s[1][r]), fmaxf(s[2][r], s[3][r]));
#pragma unroll
            for (int msk = 1; msk < 16; msk <<= 1) pm = fmaxf(pm, __shfl_xor(pm, msk));
            float mn = fmaxf(m_r[r], pm);
            fs[r] = __expf(m_r[r] - mn);
            m_r[r] = mn;
        }
        f32x4 p[4];
#pragma unroll
        for (int ch = 0; ch < 4; ++ch)
#pragma unroll
            for (int r = 0; r < 4; ++r) p[ch][r] = __expf(s[ch][r] - m_r[r]);
#pragma unroll
        for (int r = 0; r < 4; ++r) {
            float rs = p[0][r] + p[1][r] + p[2][r] + p[3][r];
#pragma unroll
            for (int msk = 1; msk < 16; msk <<= 1) rs += __shfl_xor(rs, msk);
            l_r[r] = l_r[r] * fs[r] + rs;
        }
#pragma unroll
        for (int dc = 0; dc < 4; ++dc)
#pragma unroll
            for (int r = 0; r < 4; ++r) oacc[dc][r] *= fs[r];
        // P transpose through this wave's private LDS tile (no block barrier)
#pragma unroll
        for (int ch = 0; ch < 4; ++ch)
#pragma unroll
            for (int r = 0; r < 4; ++r) pl[w][4 * lg + r][16 * ch + lr] = (__bf16)p[ch][r];
        bf16x8 pf0 = *reinterpret_cast<const bf16x8*>(&pl[w][lr][8 * lg]);
        bf16x8 pf1 = *reinterpret_cast<const bf16x8*>(&pl[w][lr][32 + 8 * lg]);
#pragma unroll
        for (int dc = 0; dc < 4; ++dc) {
            int row = 16 * dc + lr;
            bf16x8 v0 = *reinterpret_cast<const bf16x8*>(&vs[row * 64 + 8 * (lg ^ (row & 7))]);
            bf16x8 v1 = *reinterpret_cast<const bf16x8*>(&vs[row * 64 + 8 * ((4 + lg) ^ (row & 7))]);
            oacc[dc] = mfma16(pf0, v0, oacc[dc]);
            oacc[dc] = mfma16(pf1, v1, oacc[dc]);
        }
        __syncthreads();   // one barrier/iter: drains next-stage vmcnt + read fences
        cur ^= 1;
    }
    int b = bh >> 3, h = bh & 7;
#pragma unroll
    for (int dc = 0; dc < 4; ++dc)
#pragma unroll
        for (int r = 0; r < 4; ++r) {
            size_t rowg = (size_t)b * N_ + qrow + 4 * lg + r;
            Ob[rowg * INNER_ + h * DH_ + 16 * dc + lr] = (__bf16)(oacc[dc][r] / l_r[r]);
        }
}

extern "C" void kernel_launch(void* const* d_in, const int* in_sizes, int n_in,
                              void* d_out, int out_size, void* d_ws, size_t ws_size,
                              hipStream_t stream) {
    const float* x    = (const float*)d_in[0];
    const float* lnw  = (const float*)d_in[1];
    const float* lnb  = (const float*)d_in[2];
    const float* wqkv = (const float*)d_in[3];
    const float* wout = (const float*)d_in[4];
    float* out = (float*)d_out;

    char* ws = (char*)d_ws;
    size_t off = 0;
    auto alloc = [&](size_t bytes) -> char* {
        char* p = ws + off;
        off += (bytes + 255) & ~(size_t)255;
        return p;
    };
    __bf16* xn    = (__bf16*)alloc((size_t)ROWS_ * DIM_ * 2);
    __bf16* wqkvT = (__bf16*)alloc((size_t)QKVN_ * DIM_ * 2);
    __bf16* woutT = (__bf16*)alloc((size_t)DIM_ * INNER_ * 2);
    __bf16* qkvb  = (__bf16*)alloc((size_t)ROWS_ * QKVN_ * 2);
    __bf16* Qhp   = (__bf16*)alloc((size_t)B_ * H_ * N_ * DH_ * 2);
    __bf16* Khp   = (__bf16*)alloc((size_t)B_ * H_ * N_ * DH_ * 2);
    __bf16* Vtp   = (__bf16*)alloc((size_t)B_ * H_ * DH_ * N_ * 2);
    __bf16* Obp   = (__bf16*)alloc((size_t)ROWS_ * INNER_ * 2);
    if (off > ws_size) return;

    transpose_cast<<<dim3(QKVN_ / 64, DIM_ / 64), 256, 0, stream>>>(wqkv, wqkvT, DIM_, QKVN_);
    transpose_cast<<<dim3(DIM_ / 64, INNER_ / 64), 256, 0, stream>>>(wout, woutT, INNER_, DIM_);
    ln_kernel<<<ROWS_, 256, 0, stream>>>(x, lnw, lnb, xn);
    gemm_bt<__bf16><<<dim3(QKVN_ / 128, ROWS_ / 128), 256, 0, stream>>>(xn, wqkvT, qkvb, ROWS_, QKVN_, DIM_);
    heads_kernel<<<dim3(N_ / 64, B_ * H_), 256, 0, stream>>>(qkvb, Qhp, Khp, Vtp);
    attn_kernel<<<dim3(N_ / 64, B_ * H_), 256, 0, stream>>>(Qhp, Khp, Vtp, Obp);
    gemm_bt<float><<<dim3(DIM_ / 128, ROWS_ / 128), 256, 0, stream>>>(Obp, woutT, out, ROWS_, DIM_, INNER_);
}

// Round 3
// 182.851 us; speedup vs baseline: 2.0612x; 1.1128x over previous
//
#include <hip/hip_runtime.h>
#include <hip/hip_bf16.h>

typedef __attribute__((ext_vector_type(8))) __bf16 bf16x8;
typedef __attribute__((ext_vector_type(4))) __bf16 bf16x4;
typedef __attribute__((ext_vector_type(4))) float f32x4;

#define B_     2
#define N_     2048
#define DIM_   1024
#define INNER_ 512
#define H_     8
#define DH_    64
#define ROWS_  (B_ * N_)      // 4096
#define QKVN_  (3 * INNER_)   // 1536
#define SEGROWS_ 5120         // per-bh partial rows: 2048+1536+1024+512

static __device__ __forceinline__ f32x4 mfma16(bf16x8 a, bf16x8 b, f32x4 c) {
    return __builtin_amdgcn_mfma_f32_16x16x32_bf16(a, b, c, 0, 0, 0);
}

static __device__ __forceinline__ void gld_lds16(const void* g, void* l) {
    __builtin_amdgcn_global_load_lds((const __attribute__((address_space(1))) void*)g,
                                     (__attribute__((address_space(3))) void*)l, 16, 0, 0);
}

// ---------------- LayerNorm: x fp32 [4096][1024] -> xn bf16 ----------------
__global__ __launch_bounds__(256) void ln_kernel(const float* __restrict__ x,
                                                 const float* __restrict__ w,
                                                 const float* __restrict__ bb,
                                                 __bf16* __restrict__ xn) {
    int row = blockIdx.x;
    int tid = threadIdx.x;
    const float* xr = x + (size_t)row * DIM_;
    f32x4 xv = *reinterpret_cast<const f32x4*>(xr + tid * 4);
    float s  = xv.x + xv.y + xv.z + xv.w;
    float sq = xv.x * xv.x + xv.y * xv.y + xv.z * xv.z + xv.w * xv.w;
#pragma unroll
    for (int m = 1; m < 64; m <<= 1) {
        s  += __shfl_xor(s, m);
        sq += __shfl_xor(sq, m);
    }
    __shared__ float red[2][4];
    int wid = tid >> 6, lane = tid & 63;
    if (lane == 0) { red[0][wid] = s; red[1][wid] = sq; }
    __syncthreads();
    s  = red[0][0] + red[0][1] + red[0][2] + red[0][3];
    sq = red[1][0] + red[1][1] + red[1][2] + red[1][3];
    float mu   = s * (1.0f / DIM_);
    float var  = sq * (1.0f / DIM_) - mu * mu;
    float rstd = rsqrtf(var + 1e-5f);
    f32x4 wv = *reinterpret_cast<const f32x4*>(w  + tid * 4);
    f32x4 bv = *reinterpret_cast<const f32x4*>(bb + tid * 4);
    bf16x4 o;
#pragma unroll
    for (int j = 0; j < 4; ++j) o[j] = (__bf16)((xv[j] - mu) * rstd * wv[j] + bv[j]);
    *reinterpret_cast<bf16x4*>(xn + (size_t)row * DIM_ + tid * 4) = o;
}

// ---- transpose+cast (coalesced): in fp32 [K][N] -> out bf16 [N][K] --------
__global__ __launch_bounds__(256) void transpose_cast(const float* __restrict__ in,
                                                      __bf16* __restrict__ out,
                                                      int K, int N) {
    __shared__ float t[64][65];
    int n0 = blockIdx.x * 64, k0 = blockIdx.y * 64;
    int w = threadIdx.x >> 6, lane = threadIdx.x & 63;
#pragma unroll
    for (int i = 0; i < 16; ++i) {
        int k = 16 * w + i;
        t[k][lane] = in[(size_t)(k0 + k) * N + n0 + lane];
    }
    __syncthreads();
#pragma unroll
    for (int i = 0; i < 16; ++i) {
        int n = 16 * w + i;
        out[(size_t)(n0 + n) * K + k0 + lane] = (__bf16)t[lane][n];
    }
}

// ------ fused QKV GEMM: xn[4096][1024] @ wqkvT[1536][1024]^T -------------
// epilogue: l2norm rows of Q (x8) and K per head, direct head-major writes.
__global__ __launch_bounds__(256) void gemm_qkv(const __bf16* __restrict__ A,
                                                const __bf16* __restrict__ Bt,
                                                __bf16* __restrict__ Qh,
                                                __bf16* __restrict__ Kh,
                                                __bf16* __restrict__ Vrow) {
    const int K = DIM_;
    __shared__ __bf16 As[128 * 32];
    __shared__ __bf16 Bs[128 * 32];
    int tid = threadIdx.x;
    int w = tid >> 6, lane = tid & 63;
    int lr = lane & 15, lg = lane >> 4;
    int m0 = blockIdx.y * 128, n0 = blockIdx.x * 128;
    int wm = (w >> 1) * 64, wn = (w & 1) * 64;
    int srow = tid >> 2, sc = tid & 3;
    const __bf16* Ab = A  + (size_t)m0 * K;
    const __bf16* Bb = Bt + (size_t)n0 * K;
    f32x4 acc[4][4];
#pragma unroll
    for (int mi = 0; mi < 4; ++mi)
#pragma unroll
        for (int ci = 0; ci < 4; ++ci) acc[mi][ci] = f32x4{0.f, 0.f, 0.f, 0.f};
    for (int k0 = 0; k0 < K; k0 += 32) {
        __syncthreads();
#pragma unroll
        for (int q = 0; q < 2; ++q) {
            int row = q * 64 + srow;
            int cs = sc ^ (row & 3);
            gld_lds16(Ab + (size_t)row * K + k0 + 8 * cs, &As[(size_t)row * 32 + sc * 8]);
            gld_lds16(Bb + (size_t)row * K + k0 + 8 * cs, &Bs[(size_t)row * 32 + sc * 8]);
        }
        __syncthreads();
        bf16x8 af[4], bfr[4];
#pragma unroll
        for (int mi = 0; mi < 4; ++mi) {
            int r = wm + 16 * mi + lr;
            af[mi] = *reinterpret_cast<const bf16x8*>(&As[r * 32 + 8 * (lg ^ (r & 3))]);
        }
#pragma unroll
        for (int ci = 0; ci < 4; ++ci) {
            int r = wn + 16 * ci + lr;
            bfr[ci] = *reinterpret_cast<const bf16x8*>(&Bs[r * 32 + 8 * (lg ^ (r & 3))]);
        }
#pragma unroll
        for (int mi = 0; mi < 4; ++mi)
#pragma unroll
            for (int ci = 0; ci < 4; ++ci)
                acc[mi][ci] = mfma16(af[mi], bfr[ci], acc[mi][ci]);
    }
    // epilogue: wave's 64 output cols = exactly one unit (Q head/K head/V chunk)
    int u = (n0 + wn) >> 6;           // 0..23
    bool isV = (u >= 16);
    float smul = (u < 8) ? 8.0f : 1.0f;
    __bf16* base;
    if (u < 8)       base = Qh   + (size_t)u * N_ * DH_;
    else if (u < 16) base = Kh   + (size_t)(u - 8) * N_ * DH_;
    else             base = Vrow + (size_t)(u - 16) * N_ * DH_;
#pragma unroll
    for (int mi = 0; mi < 4; ++mi)
#pragma unroll
        for (int r = 0; r < 4; ++r) {
            int grow = m0 + wm + 16 * mi + 4 * lg + r;
            int b = grow >> 11, n = grow & 2047;
            float sc2 = 1.0f;
            if (!isV) {
                float t = 0.f;
#pragma unroll
                for (int ci = 0; ci < 4; ++ci) t += acc[mi][ci][r] * acc[mi][ci][r];
#pragma unroll
                for (int m = 1; m < 16; m <<= 1) t += __shfl_xor(t, m);
                sc2 = rsqrtf(t + 1e-12f) * smul;
            }
            __bf16* dst = base + ((size_t)b * H_ * N_ + n) * DH_;
#pragma unroll
            for (int ci = 0; ci < 4; ++ci)
                dst[16 * ci + lr] = (__bf16)(acc[mi][ci][r] * sc2);
        }
}

// --------- GEMM C[M][N] = A[M][K] * Bt[N][K]^T (out projection) ------------
template <typename OutT>
__global__ __launch_bounds__(256) void gemm_bt(const __bf16* __restrict__ A,
                                               const __bf16* __restrict__ Bt,
                                               OutT* __restrict__ C,
                                               int M, int N, int K) {
    __shared__ __bf16 As[128 * 32];
    __shared__ __bf16 Bs[128 * 32];
    int tid = threadIdx.x;
    int w = tid >> 6, lane = tid & 63;
    int lr = lane & 15, lg = lane >> 4;
    int m0 = blockIdx.y * 128, n0 = blockIdx.x * 128;
    int wm = (w >> 1) * 64, wn = (w & 1) * 64;
    int srow = tid >> 2, sc = tid & 3;
    const __bf16* Ab = A  + (size_t)m0 * K;
    const __bf16* Bb = Bt + (size_t)n0 * K;
    f32x4 acc[4][4];
#pragma unroll
    for (int mi = 0; mi < 4; ++mi)
#pragma unroll
        for (int ci = 0; ci < 4; ++ci) acc[mi][ci] = f32x4{0.f, 0.f, 0.f, 0.f};
    for (int k0 = 0; k0 < K; k0 += 32) {
        __syncthreads();
#pragma unroll
        for (int q = 0; q < 2; ++q) {
            int row = q * 64 + srow;
            int cs = sc ^ (row & 3);
            gld_lds16(Ab + (size_t)row * K + k0 + 8 * cs, &As[(size_t)row * 32 + sc * 8]);
            gld_lds16(Bb + (size_t)row * K + k0 + 8 * cs, &Bs[(size_t)row * 32 + sc * 8]);
        }
        __syncthreads();
        bf16x8 af[4], bfr[4];
#pragma unroll
        for (int mi = 0; mi < 4; ++mi) {
            int r = wm + 16 * mi + lr;
            af[mi] = *reinterpret_cast<const bf16x8*>(&As[r * 32 + 8 * (lg ^ (r & 3))]);
        }
#pragma unroll
        for (int ci = 0; ci < 4; ++ci) {
            int r = wn + 16 * ci + lr;
            bfr[ci] = *reinterpret_cast<const bf16x8*>(&Bs[r * 32 + 8 * (lg ^ (r & 3))]);
        }
#pragma unroll
        for (int mi = 0; mi < 4; ++mi)
#pragma unroll
            for (int ci = 0; ci < 4; ++ci)
                acc[mi][ci] = mfma16(af[mi], bfr[ci], acc[mi][ci]);
    }
#pragma unroll
    for (int mi = 0; mi < 4; ++mi)
#pragma unroll
        for (int ci = 0; ci < 4; ++ci)
#pragma unroll
            for (int r = 0; r < 4; ++r)
                C[(size_t)(m0 + wm + 16 * mi + 4 * lg + r) * N + n0 + wn + 16 * ci + lr] =
                    (OutT)acc[mi][ci][r];
}

// ------------- V transpose per head: Vrow[bh][n][64] -> Vt[bh][64][n] ------
__global__ __launch_bounds__(256) void vtrans(const __bf16* __restrict__ Vrow,
                                              __bf16* __restrict__ Vt) {
    __shared__ __bf16 t[64][66];
    int bh = blockIdx.y, n0 = blockIdx.x * 64;
    int w = threadIdx.x >> 6, lane = threadIdx.x & 63;
#pragma unroll
    for (int i = 0; i < 16; ++i) {
        int nl = 16 * w + i;
        t[nl][lane] = Vrow[((size_t)bh * N_ + n0 + nl) * DH_ + lane];
    }
    __syncthreads();
#pragma unroll
    for (int i = 0; i < 16; ++i) {
        int d = 16 * w + i;
        Vt[(size_t)bh * DH_ * N_ + (size_t)d * N_ + n0 + lane] = t[lane][d];
    }
}

// ------- causal flash attention, split-KV: 4 waves, QBLK=64, KVBLK=64 ------
// segment = up to 8 j-tiles; partial (O, m, l) written per segment.
__global__ __launch_bounds__(256) void attn_kernel(const __bf16* __restrict__ Qh,
                                                   const __bf16* __restrict__ Kh,
                                                   const __bf16* __restrict__ Vt,
                                                   float* __restrict__ Opart,
                                                   float* __restrict__ ml) {
    __shared__ __bf16 Ks[2][64 * 64];
    __shared__ __bf16 Vs[2][64 * 64];
    __shared__ __bf16 pl[4][16 * 64];   // per-wave, XOR-swizzled (no pad)
    int bh = blockIdx.x;                 // bh fastest -> heavy segments start first
    int idx = blockIdx.y;                // 0..79, heavy-first order
    int s, qt;
    if (idx < 32)      { s = 0; qt = 31 - idx; }
    else if (idx < 56) { s = 1; qt = 31 - (idx - 32); }
    else if (idx < 72) { s = 2; qt = 31 - (idx - 56); }
    else               { s = 3; qt = 31 - (idx - 72); }
    int jt0 = 8 * s;
    int jt1 = min(8 * s + 7, qt);
    int tid = threadIdx.x;
    int w = tid >> 6, lane = tid & 63;
    int lr = lane & 15, lg = lane >> 4;
    int qb = qt * 64;
    int qrow = qb + 16 * w;
    const __bf16* Qp = Qh + (size_t)bh * N_ * DH_;
    const __bf16* Kp = Kh + (size_t)bh * N_ * DH_;
    const __bf16* Vp = Vt + (size_t)bh * DH_ * N_;
    bf16x8 qf0 = *reinterpret_cast<const bf16x8*>(Qp + (size_t)(qrow + lr) * DH_ + 8 * lg);
    bf16x8 qf1 = *reinterpret_cast<const bf16x8*>(Qp + (size_t)(qrow + lr) * DH_ + 32 + 8 * lg);
    f32x4 oacc[4];
#pragma unroll
    for (int c = 0; c < 4; ++c) oacc[c] = f32x4{0.f, 0.f, 0.f, 0.f};
    float m_r[4], l_r[4];
#pragma unroll
    for (int r = 0; r < 4; ++r) { m_r[r] = -1e30f; l_r[r] = 0.f; }
    int srow = tid >> 3, sc = tid & 7;

    auto stage = [&](int buf, int jb) {
#pragma unroll
        for (int q = 0; q < 2; ++q) {
            int row = q * 32 + srow;
            int cs = sc ^ (row & 7);
            gld_lds16(Kp + (size_t)(jb + row) * DH_ + 8 * cs,
                      &Ks[buf][(size_t)row * 64 + sc * 8]);
            gld_lds16(Vp + (size_t)row * N_ + jb + 8 * cs,
                      &Vs[buf][(size_t)row * 64 + sc * 8]);
        }
    };

    stage(0, jt0 * 64);
    __syncthreads();
    int cur = 0;
    for (int jt = jt0; jt <= jt1; ++jt) {
        int jb = jt * 64;
        if (jt < jt1) stage(cur ^ 1, jb + 64);
        const __bf16* ks = &Ks[cur][0];
        const __bf16* vs = &Vs[cur][0];
        f32x4 sm[4];
#pragma unroll
        for (int ch = 0; ch < 4; ++ch) {
            int row = 16 * ch + lr;
            bf16x8 k0 = *reinterpret_cast<const bf16x8*>(&ks[row * 64 + 8 * (lg ^ (row & 7))]);
            bf16x8 k1 = *reinterpret_cast<const bf16x8*>(&ks[row * 64 + 8 * ((4 + lg) ^ (row & 7))]);
            f32x4 t = f32x4{0.f, 0.f, 0.f, 0.f};
            t = mfma16(qf0, k0, t);
            t = mfma16(qf1, k1, t);
            sm[ch] = t;
        }
        if (jt == qt) {   // diagonal tile: causal mask
#pragma unroll
            for (int ch = 0; ch < 4; ++ch)
#pragma unroll
                for (int r = 0; r < 4; ++r) {
                    int qi = qrow + 4 * lg + r;
                    int j  = jb + 16 * ch + lr;
                    if (j > qi) sm[ch][r] = -1e30f;
                }
        }
        float fs[4];
#pragma unroll
        for (int r = 0; r < 4; ++r) {
            float pm = fmaxf(fmaxf(sm[0][r], sm[1][r]), fmaxf(sm[2][r], sm[3][r]));
#pragma unroll
            for (int msk = 1; msk < 16; msk <<= 1) pm = fmaxf(pm, __shfl_xor(pm, msk));
            float mn = fmaxf(m_r[r], pm);
            fs[r] = __expf(m_r[r] - mn);
            m_r[r] = mn;
        }
        f32x4 p[4];
#pragma unroll
        for (int ch = 0; ch < 4; ++ch)
#pragma unroll
            for (int r = 0; r < 4; ++r) p[ch][r] = __expf(sm[ch][r] - m_r[r]);
#pragma unroll
        for (int r = 0; r < 4; ++r) {
            float rs = p[0][r] + p[1][r] + p[2][r] + p[3][r];
#pragma unroll
            for (int msk = 1; msk < 16; msk <<= 1) rs += __shfl_xor(rs, msk);
            l_r[r] = l_r[r] * fs[r] + rs;
        }
#pragma unroll
        for (int dc = 0; dc < 4; ++dc)
#pragma unroll
            for (int r = 0; r < 4; ++r) oacc[dc][r] *= fs[r];
        // P transpose through per-wave XOR-swizzled LDS tile
        __bf16* plw = &pl[w][0];
#pragma unroll
        for (int ch = 0; ch < 4; ++ch)
#pragma unroll
            for (int r = 0; r < 4; ++r) {
                int row = 4 * lg + r, col = 16 * ch + lr;
                plw[row * 64 + (((col >> 3) ^ (row & 7)) << 3) + (col & 7)] = (__bf16)p[ch][r];
            }
        bf16x8 pf0 = *reinterpret_cast<const bf16x8*>(&plw[lr * 64 + ((lg ^ (lr & 7)) << 3)]);
        bf16x8 pf1 = *reinterpret_cast<const bf16x8*>(&plw[lr * 64 + (((4 + lg) ^ (lr & 7)) << 3)]);
#pragma unroll
        for (int dc = 0; dc < 4; ++dc) {
            int row = 16 * dc + lr;
            bf16x8 v0 = *reinterpret_cast<const bf16x8*>(&vs[row * 64 + 8 * (lg ^ (row & 7))]);
            bf16x8 v1 = *reinterpret_cast<const bf16x8*>(&vs[row * 64 + 8 * ((4 + lg) ^ (row & 7))]);
            oacc[dc] = mfma16(pf0, v0, oacc[dc]);
            oacc[dc] = mfma16(pf1, v1, oacc[dc]);
        }
        __syncthreads();
        cur ^= 1;
    }
    // write unnormalized partial O + (m, l)
    int soff = 2048 * s - 256 * s * (s - 1);   // {0,2048,3584,4608}
#pragma unroll
    for (int r = 0; r < 4; ++r) {
        int n = qrow + 4 * lg + r;
        size_t ridx = (size_t)bh * SEGROWS_ + soff + (n - 512 * s);
#pragma unroll
        for (int dc = 0; dc < 4; ++dc)
            Opart[ridx * 64 + 16 * dc + lr] = oacc[dc][r];
        if (lr == 0) {
            ml[ridx * 2]     = m_r[r];
            ml[ridx * 2 + 1] = l_r[r];
        }
    }
}

// ----------- combine partial segments -> normalized O (bf16) ---------------
__global__ __launch_bounds__(256) void combine_kernel(const float* __restrict__ Opart,
                                                      const float* __restrict__ ml,
                                                      __bf16* __restrict__ Obp) {
    int gid = blockIdx.x * 4 + (threadIdx.x >> 6);   // q-row id 0..32767
    int lane = threadIdx.x & 63;
    int bh = gid >> 11, n = gid & 2047;
    int smax = n >> 9;                                // segments 0..smax exist
    float mstar = -1e30f;
#pragma unroll
    for (int s = 0; s < 4; ++s)
        if (s <= smax) {
            int soff = 2048 * s - 256 * s * (s - 1);
            size_t ridx = (size_t)bh * SEGROWS_ + soff + (n - 512 * s);
            mstar = fmaxf(mstar, ml[ridx * 2]);
        }
    float acc = 0.f, lsum = 0.f;
#pragma unroll
    for (int s = 0; s < 4; ++s)
        if (s <= smax) {
            int soff = 2048 * s - 256 * s * (s - 1);
            size_t ridx = (size_t)bh * SEGROWS_ + soff + (n - 512 * s);
            float wgt = __expf(ml[ridx * 2] - mstar);
            acc  += wgt * Opart[ridx * 64 + lane];
            lsum += wgt * ml[ridx * 2 + 1];
        }
    int b = bh >> 3, h = bh & 7;
    Obp[((size_t)(b * N_ + n)) * INNER_ + h * DH_ + lane] = (__bf16)(acc / lsum);
}

extern "C" void kernel_launch(void* const* d_in, const int* in_sizes, int n_in,
                              void* d_out, int out_size, void* d_ws, size_t ws_size,
                              hipStream_t stream) {
    const float* x    = (const float*)d_in[0];
    const float* lnw  = (const float*)d_in[1];
    const float* lnb  = (const float*)d_in[2];
    const float* wqkv = (const float*)d_in[3];
    const float* wout = (const float*)d_in[4];
    float* out = (float*)d_out;

    char* ws = (char*)d_ws;
    size_t off = 0;
    auto alloc = [&](size_t bytes) -> char* {
        char* p = ws + off;
        off += (bytes + 255) & ~(size_t)255;
        return p;
    };
    __bf16* xn    = (__bf16*)alloc((size_t)ROWS_ * DIM_ * 2);
    __bf16* wqkvT = (__bf16*)alloc((size_t)QKVN_ * DIM_ * 2);
    __bf16* woutT = (__bf16*)alloc((size_t)DIM_ * INNER_ * 2);
    __bf16* Qhp   = (__bf16*)alloc((size_t)B_ * H_ * N_ * DH_ * 2);
    __bf16* Khp   = (__bf16*)alloc((size_t)B_ * H_ * N_ * DH_ * 2);
    __bf16* Vrow  = (__bf16*)alloc((size_t)B_ * H_ * N_ * DH_ * 2);
    __bf16* Vtp   = (__bf16*)alloc((size_t)B_ * H_ * DH_ * N_ * 2);
    __bf16* Obp   = (__bf16*)alloc((size_t)ROWS_ * INNER_ * 2);
    float*  Opart = (float*)alloc((size_t)B_ * H_ * SEGROWS_ * DH_ * 4);
    float*  mlb   = (float*)alloc((size_t)B_ * H_ * SEGROWS_ * 2 * 4);
    if (off > ws_size) return;

    transpose_cast<<<dim3(QKVN_ / 64, DIM_ / 64), 256, 0, stream>>>(wqkv, wqkvT, DIM_, QKVN_);
    transpose_cast<<<dim3(DIM_ / 64, INNER_ / 64), 256, 0, stream>>>(wout, woutT, INNER_, DIM_);
    ln_kernel<<<ROWS_, 256, 0, stream>>>(x, lnw, lnb, xn);
    gemm_qkv<<<dim3(QKVN_ / 128, ROWS_ / 128), 256, 0, stream>>>(xn, wqkvT, Qhp, Khp, Vrow);
    vtrans<<<dim3(N_ / 64, B_ * H_), 256, 0, stream>>>(Vrow, Vtp);
    attn_kernel<<<dim3(B_ * H_, 80), 256, 0, stream>>>(Qhp, Khp, Vtp, Opart, mlb);
    combine_kernel<<<(ROWS_ * H_) / 4, 256, 0, stream>>>(Opart, mlb, Obp);
    gemm_bt<float><<<dim3(DIM_ / 128, ROWS_ / 128), 256, 0, stream>>>(Obp, woutT, out, ROWS_, DIM_, INNER_);
}

// Round 4
// 168.200 us; speedup vs baseline: 2.2407x; 1.0871x over previous
//
#include <hip/hip_runtime.h>
#include <hip/hip_bf16.h>

typedef __attribute__((ext_vector_type(8))) __bf16 bf16x8;
typedef __attribute__((ext_vector_type(4))) __bf16 bf16x4;
typedef __attribute__((ext_vector_type(4))) float f32x4;

#define B_     2
#define N_     2048
#define DIM_   1024
#define INNER_ 512
#define H_     8
#define DH_    64
#define ROWS_  (B_ * N_)      // 4096
#define QKVN_  (3 * INNER_)   // 1536
#define SEGROWS_ 5120         // per-bh partial rows: 2048+1536+1024+512
#define QSCALE_ 11.5415603f   // 8 * log2(e): exp2-domain cosine scale
#define MAXL2_  11.5415603f   // fixed softmax max in exp2 domain

static __device__ __forceinline__ f32x4 mfma16(bf16x8 a, bf16x8 b, f32x4 c) {
    return __builtin_amdgcn_mfma_f32_16x16x32_bf16(a, b, c, 0, 0, 0);
}

static __device__ __forceinline__ void gld_lds16(const void* g, void* l) {
    __builtin_amdgcn_global_load_lds((const __attribute__((address_space(1))) void*)g,
                                     (__attribute__((address_space(3))) void*)l, 16, 0, 0);
}

// ---------------- LayerNorm: x fp32 [4096][1024] -> xn bf16 ----------------
__global__ __launch_bounds__(256) void ln_kernel(const float* __restrict__ x,
                                                 const float* __restrict__ w,
                                                 const float* __restrict__ bb,
                                                 __bf16* __restrict__ xn) {
    int row = blockIdx.x;
    int tid = threadIdx.x;
    const float* xr = x + (size_t)row * DIM_;
    f32x4 xv = *reinterpret_cast<const f32x4*>(xr + tid * 4);
    float s  = xv.x + xv.y + xv.z + xv.w;
    float sq = xv.x * xv.x + xv.y * xv.y + xv.z * xv.z + xv.w * xv.w;
#pragma unroll
    for (int m = 1; m < 64; m <<= 1) {
        s  += __shfl_xor(s, m);
        sq += __shfl_xor(sq, m);
    }
    __shared__ float red[2][4];
    int wid = tid >> 6, lane = tid & 63;
    if (lane == 0) { red[0][wid] = s; red[1][wid] = sq; }
    __syncthreads();
    s  = red[0][0] + red[0][1] + red[0][2] + red[0][3];
    sq = red[1][0] + red[1][1] + red[1][2] + red[1][3];
    float mu   = s * (1.0f / DIM_);
    float var  = sq * (1.0f / DIM_) - mu * mu;
    float rstd = rsqrtf(var + 1e-5f);
    f32x4 wv = *reinterpret_cast<const f32x4*>(w  + tid * 4);
    f32x4 bv = *reinterpret_cast<const f32x4*>(bb + tid * 4);
    bf16x4 o;
#pragma unroll
    for (int j = 0; j < 4; ++j) o[j] = (__bf16)((xv[j] - mu) * rstd * wv[j] + bv[j]);
    *reinterpret_cast<bf16x4*>(xn + (size_t)row * DIM_ + tid * 4) = o;
}

// ---- transpose+cast (coalesced): in fp32 [K][N] -> out bf16 [N][K] --------
__global__ __launch_bounds__(256) void transpose_cast(const float* __restrict__ in,
                                                      __bf16* __restrict__ out,
                                                      int K, int N) {
    __shared__ float t[64][65];
    int n0 = blockIdx.x * 64, k0 = blockIdx.y * 64;
    int w = threadIdx.x >> 6, lane = threadIdx.x & 63;
#pragma unroll
    for (int i = 0; i < 16; ++i) {
        int k = 16 * w + i;
        t[k][lane] = in[(size_t)(k0 + k) * N + n0 + lane];
    }
    __syncthreads();
#pragma unroll
    for (int i = 0; i < 16; ++i) {
        int n = 16 * w + i;
        out[(size_t)(n0 + n) * K + k0 + lane] = (__bf16)t[lane][n];
    }
}

// ------ fused QKV GEMM: xn[4096][1024] @ wqkvT[1536][1024]^T ---------------
// epilogue: l2norm rows of Q (xQSCALE_) and K per head, head-major writes.
__global__ __launch_bounds__(256) void gemm_qkv(const __bf16* __restrict__ A,
                                                const __bf16* __restrict__ Bt,
                                                __bf16* __restrict__ Qh,
                                                __bf16* __restrict__ Kh,
                                                __bf16* __restrict__ Vrow) {
    const int K = DIM_;
    __shared__ __bf16 As[128 * 32];
    __shared__ __bf16 Bs[128 * 32];
    int tid = threadIdx.x;
    int w = tid >> 6, lane = tid & 63;
    int lr = lane & 15, lg = lane >> 4;
    int m0 = blockIdx.y * 128, n0 = blockIdx.x * 128;
    int wm = (w >> 1) * 64, wn = (w & 1) * 64;
    int srow = tid >> 2, sc = tid & 3;
    const __bf16* Ab = A  + (size_t)m0 * K;
    const __bf16* Bb = Bt + (size_t)n0 * K;
    f32x4 acc[4][4];
#pragma unroll
    for (int mi = 0; mi < 4; ++mi)
#pragma unroll
        for (int ci = 0; ci < 4; ++ci) acc[mi][ci] = f32x4{0.f, 0.f, 0.f, 0.f};
    for (int k0 = 0; k0 < K; k0 += 32) {
        __syncthreads();
#pragma unroll
        for (int q = 0; q < 2; ++q) {
            int row = q * 64 + srow;
            int cs = sc ^ (row & 3);
            gld_lds16(Ab + (size_t)row * K + k0 + 8 * cs, &As[(size_t)row * 32 + sc * 8]);
            gld_lds16(Bb + (size_t)row * K + k0 + 8 * cs, &Bs[(size_t)row * 32 + sc * 8]);
        }
        __syncthreads();
        bf16x8 af[4], bfr[4];
#pragma unroll
        for (int mi = 0; mi < 4; ++mi) {
            int r = wm + 16 * mi + lr;
            af[mi] = *reinterpret_cast<const bf16x8*>(&As[r * 32 + 8 * (lg ^ (r & 3))]);
        }
#pragma unroll
        for (int ci = 0; ci < 4; ++ci) {
            int r = wn + 16 * ci + lr;
            bfr[ci] = *reinterpret_cast<const bf16x8*>(&Bs[r * 32 + 8 * (lg ^ (r & 3))]);
        }
#pragma unroll
        for (int mi = 0; mi < 4; ++mi)
#pragma unroll
            for (int ci = 0; ci < 4; ++ci)
                acc[mi][ci] = mfma16(af[mi], bfr[ci], acc[mi][ci]);
    }
    int u = (n0 + wn) >> 6;           // 0..23: Q heads 0-7, K heads 8-15, V 16-23
    bool isV = (u >= 16);
    float smul = (u < 8) ? QSCALE_ : 1.0f;
    __bf16* base;
    if (u < 8)       base = Qh   + (size_t)u * N_ * DH_;
    else if (u < 16) base = Kh   + (size_t)(u - 8) * N_ * DH_;
    else             base = Vrow + (size_t)(u - 16) * N_ * DH_;
#pragma unroll
    for (int mi = 0; mi < 4; ++mi)
#pragma unroll
        for (int r = 0; r < 4; ++r) {
            int grow = m0 + wm + 16 * mi + 4 * lg + r;
            int b = grow >> 11, n = grow & 2047;
            float sc2 = 1.0f;
            if (!isV) {
                float t = 0.f;
#pragma unroll
                for (int ci = 0; ci < 4; ++ci) t += acc[mi][ci][r] * acc[mi][ci][r];
#pragma unroll
                for (int m = 1; m < 16; m <<= 1) t += __shfl_xor(t, m);
                sc2 = rsqrtf(t + 1e-12f) * smul;
            }
            __bf16* dst = base + ((size_t)b * H_ * N_ + n) * DH_;
#pragma unroll
            for (int ci = 0; ci < 4; ++ci)
                dst[16 * ci + lr] = (__bf16)(acc[mi][ci][r] * sc2);
        }
}

// --------- GEMM C[M][N] = A[M][K] * Bt[N][K]^T (out projection) ------------
template <typename OutT>
__global__ __launch_bounds__(256) void gemm_bt(const __bf16* __restrict__ A,
                                               const __bf16* __restrict__ Bt,
                                               OutT* __restrict__ C,
                                               int M, int N, int K) {
    __shared__ __bf16 As[128 * 32];
    __shared__ __bf16 Bs[128 * 32];
    int tid = threadIdx.x;
    int w = tid >> 6, lane = tid & 63;
    int lr = lane & 15, lg = lane >> 4;
    int m0 = blockIdx.y * 128, n0 = blockIdx.x * 128;
    int wm = (w >> 1) * 64, wn = (w & 1) * 64;
    int srow = tid >> 2, sc = tid & 3;
    const __bf16* Ab = A  + (size_t)m0 * K;
    const __bf16* Bb = Bt + (size_t)n0 * K;
    f32x4 acc[4][4];
#pragma unroll
    for (int mi = 0; mi < 4; ++mi)
#pragma unroll
        for (int ci = 0; ci < 4; ++ci) acc[mi][ci] = f32x4{0.f, 0.f, 0.f, 0.f};
    for (int k0 = 0; k0 < K; k0 += 32) {
        __syncthreads();
#pragma unroll
        for (int q = 0; q < 2; ++q) {
            int row = q * 64 + srow;
            int cs = sc ^ (row & 3);
            gld_lds16(Ab + (size_t)row * K + k0 + 8 * cs, &As[(size_t)row * 32 + sc * 8]);
            gld_lds16(Bb + (size_t)row * K + k0 + 8 * cs, &Bs[(size_t)row * 32 + sc * 8]);
        }
        __syncthreads();
        bf16x8 af[4], bfr[4];
#pragma unroll
        for (int mi = 0; mi < 4; ++mi) {
            int r = wm + 16 * mi + lr;
            af[mi] = *reinterpret_cast<const bf16x8*>(&As[r * 32 + 8 * (lg ^ (r & 3))]);
        }
#pragma unroll
        for (int ci = 0; ci < 4; ++ci) {
            int r = wn + 16 * ci + lr;
            bfr[ci] = *reinterpret_cast<const bf16x8*>(&Bs[r * 32 + 8 * (lg ^ (r & 3))]);
        }
#pragma unroll
        for (int mi = 0; mi < 4; ++mi)
#pragma unroll
            for (int ci = 0; ci < 4; ++ci)
                acc[mi][ci] = mfma16(af[mi], bfr[ci], acc[mi][ci]);
    }
#pragma unroll
    for (int mi = 0; mi < 4; ++mi)
#pragma unroll
        for (int ci = 0; ci < 4; ++ci)
#pragma unroll
            for (int r = 0; r < 4; ++r)
                C[(size_t)(m0 + wm + 16 * mi + 4 * lg + r) * N + n0 + wn + 16 * ci + lr] =
                    (OutT)acc[mi][ci][r];
}

// ------------- V transpose per head: Vrow[bh][n][64] -> Vt[bh][64][n] ------
__global__ __launch_bounds__(256) void vtrans(const __bf16* __restrict__ Vrow,
                                              __bf16* __restrict__ Vt) {
    __shared__ __bf16 t[64][66];
    int bh = blockIdx.y, n0 = blockIdx.x * 64;
    int w = threadIdx.x >> 6, lane = threadIdx.x & 63;
#pragma unroll
    for (int i = 0; i < 16; ++i) {
        int nl = 16 * w + i;
        t[nl][lane] = Vrow[((size_t)bh * N_ + n0 + nl) * DH_ + lane];
    }
    __syncthreads();
#pragma unroll
    for (int i = 0; i < 16; ++i) {
        int d = 16 * w + i;
        Vt[(size_t)bh * DH_ * N_ + (size_t)d * N_ + n0 + lane] = t[lane][d];
    }
}

// ------- causal flash attention, split-KV, FIXED-MAX softmax ---------------
// |S| <= 8 (cosine sim) => no online max. p = exp2(S' - MAXL2_), S' in exp2
// domain (QSCALE_ folded into Q). Row-sum l via ones-column MFMA (no shfls).
__global__ __launch_bounds__(256) void attn_kernel(const __bf16* __restrict__ Qh,
                                                   const __bf16* __restrict__ Kh,
                                                   const __bf16* __restrict__ Vt,
                                                   float* __restrict__ Opart,
                                                   float* __restrict__ lpart) {
    __shared__ __bf16 Ks[2][64 * 64];
    __shared__ __bf16 Vs[2][64 * 64];
    __shared__ __bf16 pl[4][16 * 64];   // per-wave, XOR-swizzled
    int bh  = blockIdx.x & 15;
    int sid = blockIdx.x >> 4;           // 0..79, heavy-first order
    int s, qt;
    if (sid < 32)      { s = 0; qt = 31 - sid; }
    else if (sid < 56) { s = 1; qt = 31 - (sid - 32); }
    else if (sid < 72) { s = 2; qt = 31 - (sid - 56); }
    else               { s = 3; qt = 31 - (sid - 72); }
    int jt0 = 8 * s;
    int jt1 = min(8 * s + 7, qt);
    int tid = threadIdx.x;
    int w = tid >> 6, lane = tid & 63;
    int lr = lane & 15, lg = lane >> 4;
    int qrow = qt * 64 + 16 * w;
    const __bf16* Qp = Qh + (size_t)bh * N_ * DH_;
    const __bf16* Kp = Kh + (size_t)bh * N_ * DH_;
    const __bf16* Vp = Vt + (size_t)bh * DH_ * N_;
    bf16x8 qf0 = *reinterpret_cast<const bf16x8*>(Qp + (size_t)(qrow + lr) * DH_ + 8 * lg);
    bf16x8 qf1 = *reinterpret_cast<const bf16x8*>(Qp + (size_t)(qrow + lr) * DH_ + 32 + 8 * lg);
    bf16x8 ones;
#pragma unroll
    for (int j = 0; j < 8; ++j) ones[j] = (__bf16)1.0f;
    f32x4 oacc[4];
    f32x4 oacc4 = f32x4{0.f, 0.f, 0.f, 0.f};   // ones-column: row sums (l)
#pragma unroll
    for (int c = 0; c < 4; ++c) oacc[c] = f32x4{0.f, 0.f, 0.f, 0.f};
    int srow = tid >> 3, sc = tid & 7;

    auto stage = [&](int buf, int jb) {
#pragma unroll
        for (int q = 0; q < 2; ++q) {
            int row = q * 32 + srow;
            int cs = sc ^ (row & 7);
            gld_lds16(Kp + (size_t)(jb + row) * DH_ + 8 * cs,
                      &Ks[buf][(size_t)row * 64 + sc * 8]);
            gld_lds16(Vp + (size_t)row * N_ + jb + 8 * cs,
                      &Vs[buf][(size_t)row * 64 + sc * 8]);
        }
    };

    stage(0, jt0 * 64);
    __syncthreads();
    int cur = 0;
    for (int jt = jt0; jt <= jt1; ++jt) {
        int jb = jt * 64;
        if (jt < jt1) stage(cur ^ 1, jb + 64);
        const __bf16* ks = &Ks[cur][0];
        const __bf16* vs = &Vs[cur][0];
        f32x4 sm[4];
#pragma unroll
        for (int ch = 0; ch < 4; ++ch) {
            int row = 16 * ch + lr;
            bf16x8 k0 = *reinterpret_cast<const bf16x8*>(&ks[row * 64 + 8 * (lg ^ (row & 7))]);
            bf16x8 k1 = *reinterpret_cast<const bf16x8*>(&ks[row * 64 + 8 * ((4 + lg) ^ (row & 7))]);
            f32x4 t = f32x4{0.f, 0.f, 0.f, 0.f};
            t = mfma16(qf0, k0, t);
            t = mfma16(qf1, k1, t);
            sm[ch] = t;
        }
        // p = exp2(s - MAXL2_); masked entries -> 0
        f32x4 p[4];
        bool diag = (jt == qt);
#pragma unroll
        for (int ch = 0; ch < 4; ++ch)
#pragma unroll
            for (int r = 0; r < 4; ++r) {
                float pv = exp2f(sm[ch][r] - MAXL2_);
                if (diag) {
                    int qi = qrow + 4 * lg + r;
                    int j  = jb + 16 * ch + lr;
                    if (j > qi) pv = 0.f;
                }
                p[ch][r] = pv;
            }
        // P transpose through per-wave XOR-swizzled LDS tile
        __bf16* plw = &pl[w][0];
#pragma unroll
        for (int ch = 0; ch < 4; ++ch)
#pragma unroll
            for (int r = 0; r < 4; ++r) {
                int row = 4 * lg + r, col = 16 * ch + lr;
                plw[row * 64 + (((col >> 3) ^ (row & 7)) << 3) + (col & 7)] = (__bf16)p[ch][r];
            }
        bf16x8 pf0 = *reinterpret_cast<const bf16x8*>(&plw[lr * 64 + ((lg ^ (lr & 7)) << 3)]);
        bf16x8 pf1 = *reinterpret_cast<const bf16x8*>(&plw[lr * 64 + (((4 + lg) ^ (lr & 7)) << 3)]);
#pragma unroll
        for (int dc = 0; dc < 4; ++dc) {
            int row = 16 * dc + lr;
            bf16x8 v0 = *reinterpret_cast<const bf16x8*>(&vs[row * 64 + 8 * (lg ^ (row & 7))]);
            bf16x8 v1 = *reinterpret_cast<const bf16x8*>(&vs[row * 64 + 8 * ((4 + lg) ^ (row & 7))]);
            oacc[dc] = mfma16(pf0, v0, oacc[dc]);
            oacc[dc] = mfma16(pf1, v1, oacc[dc]);
        }
        oacc4 = mfma16(pf0, ones, oacc4);   // l += row-sum(P)
        oacc4 = mfma16(pf1, ones, oacc4);
        __syncthreads();
        cur ^= 1;
    }
    // write unnormalized partial O + l
    int soff = 2048 * s - 256 * s * (s - 1);   // {0,2048,3584,4608}
#pragma unroll
    for (int r = 0; r < 4; ++r) {
        int n = qrow + 4 * lg + r;
        size_t ridx = (size_t)bh * SEGROWS_ + soff + (n - 512 * s);
#pragma unroll
        for (int dc = 0; dc < 4; ++dc)
            Opart[ridx * 64 + 16 * dc + lr] = oacc[dc][r];
        if (lr == 0) lpart[ridx] = oacc4[r];
    }
}

// ----------- combine partial segments -> normalized O (bf16) ---------------
__global__ __launch_bounds__(256) void combine_kernel(const float* __restrict__ Opart,
                                                      const float* __restrict__ lpart,
                                                      __bf16* __restrict__ Obp) {
    int gid = blockIdx.x * 4 + (threadIdx.x >> 6);   // q-row id 0..32767
    int lane = threadIdx.x & 63;
    int bh = gid >> 11, n = gid & 2047;
    int smax = n >> 9;
    float acc = 0.f, lsum = 0.f;
#pragma unroll
    for (int s = 0; s < 4; ++s)
        if (s <= smax) {
            int soff = 2048 * s - 256 * s * (s - 1);
            size_t ridx = (size_t)bh * SEGROWS_ + soff + (n - 512 * s);
            acc  += Opart[ridx * 64 + lane];
            lsum += lpart[ridx];
        }
    int b = bh >> 3, h = bh & 7;
    Obp[((size_t)(b * N_ + n)) * INNER_ + h * DH_ + lane] = (__bf16)(acc / lsum);
}

extern "C" void kernel_launch(void* const* d_in, const int* in_sizes, int n_in,
                              void* d_out, int out_size, void* d_ws, size_t ws_size,
                              hipStream_t stream) {
    const float* x    = (const float*)d_in[0];
    const float* lnw  = (const float*)d_in[1];
    const float* lnb  = (const float*)d_in[2];
    const float* wqkv = (const float*)d_in[3];
    const float* wout = (const float*)d_in[4];
    float* out = (float*)d_out;

    char* ws = (char*)d_ws;
    size_t off = 0;
    auto alloc = [&](size_t bytes) -> char* {
        char* p = ws + off;
        off += (bytes + 255) & ~(size_t)255;
        return p;
    };
    __bf16* xn    = (__bf16*)alloc((size_t)ROWS_ * DIM_ * 2);
    __bf16* wqkvT = (__bf16*)alloc((size_t)QKVN_ * DIM_ * 2);
    __bf16* woutT = (__bf16*)alloc((size_t)DIM_ * INNER_ * 2);
    __bf16* Qhp   = (__bf16*)alloc((size_t)B_ * H_ * N_ * DH_ * 2);
    __bf16* Khp   = (__bf16*)alloc((size_t)B_ * H_ * N_ * DH_ * 2);
    __bf16* Vrow  = (__bf16*)alloc((size_t)B_ * H_ * N_ * DH_ * 2);
    __bf16* Vtp   = (__bf16*)alloc((size_t)B_ * H_ * DH_ * N_ * 2);
    __bf16* Obp   = (__bf16*)alloc((size_t)ROWS_ * INNER_ * 2);
    float*  Opart = (float*)alloc((size_t)B_ * H_ * SEGROWS_ * DH_ * 4);
    float*  lbuf  = (float*)alloc((size_t)B_ * H_ * SEGROWS_ * 4);
    if (off > ws_size) return;

    transpose_cast<<<dim3(QKVN_ / 64, DIM_ / 64), 256, 0, stream>>>(wqkv, wqkvT, DIM_, QKVN_);
    transpose_cast<<<dim3(DIM_ / 64, INNER_ / 64), 256, 0, stream>>>(wout, woutT, INNER_, DIM_);
    ln_kernel<<<ROWS_, 256, 0, stream>>>(x, lnw, lnb, xn);
    gemm_qkv<<<dim3(QKVN_ / 128, ROWS_ / 128), 256, 0, stream>>>(xn, wqkvT, Qhp, Khp, Vrow);
    vtrans<<<dim3(N_ / 64, B_ * H_), 256, 0, stream>>>(Vrow, Vtp);
    attn_kernel<<<1280, 256, 0, stream>>>(Qhp, Khp, Vtp, Opart, lbuf);
    combine_kernel<<<(ROWS_ * H_) / 4, 256, 0, stream>>>(Opart, lbuf, Obp);
    gemm_bt<float><<<dim3(DIM_ / 128, ROWS_ / 128), 256, 0, stream>>>(Obp, woutT, out, ROWS_, DIM_, INNER_);
}

// Round 5
// 166.849 us; speedup vs baseline: 2.2588x; 1.0081x over previous
//
#include <hip/hip_runtime.h>
#include <hip/hip_bf16.h>

typedef __attribute__((ext_vector_type(8))) __bf16 bf16x8;
typedef __attribute__((ext_vector_type(4))) __bf16 bf16x4;
typedef __attribute__((ext_vector_type(4))) float f32x4;

#define B_     2
#define N_     2048
#define DIM_   1024
#define INNER_ 512
#define H_     8
#define DH_    64
#define ROWS_  (B_ * N_)      // 4096
#define QKVN_  (3 * INNER_)   // 1536
#define SEGROWS_ 5120         // per-bh partial rows: 2048+1536+1024+512
#define QSCALE_ 11.5415603f   // 8 * log2(e): exp2-domain cosine scale
#define MAXL2_  11.5415603f   // fixed softmax max in exp2 domain

static __device__ __forceinline__ f32x4 mfma16(bf16x8 a, bf16x8 b, f32x4 c) {
    return __builtin_amdgcn_mfma_f32_16x16x32_bf16(a, b, c, 0, 0, 0);
}

static __device__ __forceinline__ void gld_lds16(const void* g, void* l) {
    __builtin_amdgcn_global_load_lds((const __attribute__((address_space(1))) void*)g,
                                     (__attribute__((address_space(3))) void*)l, 16, 0, 0);
}

// ---------------- LayerNorm: x fp32 [4096][1024] -> xn bf16 ----------------
__global__ __launch_bounds__(256) void ln_kernel(const float* __restrict__ x,
                                                 const float* __restrict__ w,
                                                 const float* __restrict__ bb,
                                                 __bf16* __restrict__ xn) {
    int row = blockIdx.x;
    int tid = threadIdx.x;
    const float* xr = x + (size_t)row * DIM_;
    f32x4 xv = *reinterpret_cast<const f32x4*>(xr + tid * 4);
    float s  = xv.x + xv.y + xv.z + xv.w;
    float sq = xv.x * xv.x + xv.y * xv.y + xv.z * xv.z + xv.w * xv.w;
#pragma unroll
    for (int m = 1; m < 64; m <<= 1) {
        s  += __shfl_xor(s, m);
        sq += __shfl_xor(sq, m);
    }
    __shared__ float red[2][4];
    int wid = tid >> 6, lane = tid & 63;
    if (lane == 0) { red[0][wid] = s; red[1][wid] = sq; }
    __syncthreads();
    s  = red[0][0] + red[0][1] + red[0][2] + red[0][3];
    sq = red[1][0] + red[1][1] + red[1][2] + red[1][3];
    float mu   = s * (1.0f / DIM_);
    float var  = sq * (1.0f / DIM_) - mu * mu;
    float rstd = rsqrtf(var + 1e-5f);
    f32x4 wv = *reinterpret_cast<const f32x4*>(w  + tid * 4);
    f32x4 bv = *reinterpret_cast<const f32x4*>(bb + tid * 4);
    bf16x4 o;
#pragma unroll
    for (int j = 0; j < 4; ++j) o[j] = (__bf16)((xv[j] - mu) * rstd * wv[j] + bv[j]);
    *reinterpret_cast<bf16x4*>(xn + (size_t)row * DIM_ + tid * 4) = o;
}

// ---- both weight transposes in ONE launch: fp32 [K][N] -> bf16 [N][K] -----
__global__ __launch_bounds__(256) void transpose_both(const float* __restrict__ wqkv,
                                                      const float* __restrict__ wout,
                                                      __bf16* __restrict__ wqkvT,
                                                      __bf16* __restrict__ woutT) {
    __shared__ float t[64][65];
    int bid = blockIdx.x;
    const float* in; __bf16* out; int K, N, bx, by;
    if (bid < 384) { in = wqkv; out = wqkvT; K = DIM_;   N = QKVN_; bx = bid % 24; by = bid / 24; }
    else { bid -= 384; in = wout; out = woutT; K = INNER_; N = DIM_;  bx = bid % 16; by = bid / 16; }
    int n0 = bx * 64, k0 = by * 64;
    int w = threadIdx.x >> 6, lane = threadIdx.x & 63;
#pragma unroll
    for (int i = 0; i < 16; ++i) {
        int k = 16 * w + i;
        t[k][lane] = in[(size_t)(k0 + k) * N + n0 + lane];
    }
    __syncthreads();
#pragma unroll
    for (int i = 0; i < 16; ++i) {
        int n = 16 * w + i;
        out[(size_t)(n0 + n) * K + k0 + lane] = (__bf16)t[lane][n];
    }
}

// ------ fused QKV GEMM (2-phase dbuf): xn @ wqkvT^T, l2norm epilogue -------
__global__ __launch_bounds__(256) void gemm_qkv(const __bf16* __restrict__ A,
                                                const __bf16* __restrict__ Bt,
                                                __bf16* __restrict__ Qh,
                                                __bf16* __restrict__ Kh,
                                                __bf16* __restrict__ Vrow) {
    const int K = DIM_;
    __shared__ __bf16 As[2][128 * 32];
    __shared__ __bf16 Bs[2][128 * 32];
    int tid = threadIdx.x;
    int w = tid >> 6, lane = tid & 63;
    int lr = lane & 15, lg = lane >> 4;
    int m0 = blockIdx.y * 128, n0 = blockIdx.x * 128;
    int wm = (w >> 1) * 64, wn = (w & 1) * 64;
    int srow = tid >> 2, sc = tid & 3;
    const __bf16* Ab = A  + (size_t)m0 * K;
    const __bf16* Bb = Bt + (size_t)n0 * K;
    f32x4 acc[4][4];
#pragma unroll
    for (int mi = 0; mi < 4; ++mi)
#pragma unroll
        for (int ci = 0; ci < 4; ++ci) acc[mi][ci] = f32x4{0.f, 0.f, 0.f, 0.f};

    auto stage = [&](int buf, int k0) {
#pragma unroll
        for (int q = 0; q < 2; ++q) {
            int row = q * 64 + srow;
            int cs = sc ^ (row & 3);
            gld_lds16(Ab + (size_t)row * K + k0 + 8 * cs, &As[buf][(size_t)row * 32 + sc * 8]);
            gld_lds16(Bb + (size_t)row * K + k0 + 8 * cs, &Bs[buf][(size_t)row * 32 + sc * 8]);
        }
    };

    stage(0, 0);
    __syncthreads();
    int cur = 0;
    for (int k0 = 0; k0 < K; k0 += 32) {
        if (k0 + 32 < K) stage(cur ^ 1, k0 + 32);   // issue next; completes under MFMA
        bf16x8 af[4], bfr[4];
#pragma unroll
        for (int mi = 0; mi < 4; ++mi) {
            int r = wm + 16 * mi + lr;
            af[mi] = *reinterpret_cast<const bf16x8*>(&As[cur][r * 32 + 8 * (lg ^ (r & 3))]);
        }
#pragma unroll
        for (int ci = 0; ci < 4; ++ci) {
            int r = wn + 16 * ci + lr;
            bfr[ci] = *reinterpret_cast<const bf16x8*>(&Bs[cur][r * 32 + 8 * (lg ^ (r & 3))]);
        }
#pragma unroll
        for (int mi = 0; mi < 4; ++mi)
#pragma unroll
            for (int ci = 0; ci < 4; ++ci)
                acc[mi][ci] = mfma16(af[mi], bfr[ci], acc[mi][ci]);
        __syncthreads();   // single barrier/step: drains next stage + read fence
        cur ^= 1;
    }
    int u = (n0 + wn) >> 6;           // 0..23: Q heads 0-7, K heads 8-15, V 16-23
    bool isV = (u >= 16);
    float smul = (u < 8) ? QSCALE_ : 1.0f;
    __bf16* base;
    if (u < 8)       base = Qh   + (size_t)u * N_ * DH_;
    else if (u < 16) base = Kh   + (size_t)(u - 8) * N_ * DH_;
    else             base = Vrow + (size_t)(u - 16) * N_ * DH_;
#pragma unroll
    for (int mi = 0; mi < 4; ++mi)
#pragma unroll
        for (int r = 0; r < 4; ++r) {
            int grow = m0 + wm + 16 * mi + 4 * lg + r;
            int b = grow >> 11, n = grow & 2047;
            float sc2 = 1.0f;
            if (!isV) {
                float t = 0.f;
#pragma unroll
                for (int ci = 0; ci < 4; ++ci) t += acc[mi][ci][r] * acc[mi][ci][r];
#pragma unroll
                for (int m = 1; m < 16; m <<= 1) t += __shfl_xor(t, m);
                sc2 = rsqrtf(t + 1e-12f) * smul;
            }
            __bf16* dst = base + ((size_t)b * H_ * N_ + n) * DH_;
#pragma unroll
            for (int ci = 0; ci < 4; ++ci)
                dst[16 * ci + lr] = (__bf16)(acc[mi][ci][r] * sc2);
        }
}

// ---- out-proj GEMM (2-phase dbuf, 128x64 tile for 2x grid parallelism) ----
__global__ __launch_bounds__(256) void gemm_out(const __bf16* __restrict__ A,
                                                const __bf16* __restrict__ Bt,
                                                float* __restrict__ C) {
    const int K = INNER_, N = DIM_;
    __shared__ __bf16 As[2][128 * 32];
    __shared__ __bf16 Bs[2][64 * 32];
    int tid = threadIdx.x;
    int w = tid >> 6, lane = tid & 63;
    int lr = lane & 15, lg = lane >> 4;
    int m0 = blockIdx.y * 128, n0 = blockIdx.x * 64;
    int wm = w * 32;
    int srow = tid >> 2, sc = tid & 3;
    const __bf16* Ab = A  + (size_t)m0 * K;
    const __bf16* Bb = Bt + (size_t)n0 * K;
    f32x4 acc[2][4];
#pragma unroll
    for (int mi = 0; mi < 2; ++mi)
#pragma unroll
        for (int ci = 0; ci < 4; ++ci) acc[mi][ci] = f32x4{0.f, 0.f, 0.f, 0.f};

    auto stage = [&](int buf, int k0) {
#pragma unroll
        for (int q = 0; q < 2; ++q) {
            int row = q * 64 + srow;
            int cs = sc ^ (row & 3);
            gld_lds16(Ab + (size_t)row * K + k0 + 8 * cs, &As[buf][(size_t)row * 32 + sc * 8]);
        }
        {
            int row = srow;
            int cs = sc ^ (row & 3);
            gld_lds16(Bb + (size_t)row * K + k0 + 8 * cs, &Bs[buf][(size_t)row * 32 + sc * 8]);
        }
    };

    stage(0, 0);
    __syncthreads();
    int cur = 0;
    for (int k0 = 0; k0 < K; k0 += 32) {
        if (k0 + 32 < K) stage(cur ^ 1, k0 + 32);
        bf16x8 af[2], bfr[4];
#pragma unroll
        for (int mi = 0; mi < 2; ++mi) {
            int r = wm + 16 * mi + lr;
            af[mi] = *reinterpret_cast<const bf16x8*>(&As[cur][r * 32 + 8 * (lg ^ (r & 3))]);
        }
#pragma unroll
        for (int ci = 0; ci < 4; ++ci) {
            int r = 16 * ci + lr;
            bfr[ci] = *reinterpret_cast<const bf16x8*>(&Bs[cur][r * 32 + 8 * (lg ^ (r & 3))]);
        }
#pragma unroll
        for (int mi = 0; mi < 2; ++mi)
#pragma unroll
            for (int ci = 0; ci < 4; ++ci)
                acc[mi][ci] = mfma16(af[mi], bfr[ci], acc[mi][ci]);
        __syncthreads();
        cur ^= 1;
    }
#pragma unroll
    for (int mi = 0; mi < 2; ++mi)
#pragma unroll
        for (int ci = 0; ci < 4; ++ci)
#pragma unroll
            for (int r = 0; r < 4; ++r)
                C[(size_t)(m0 + wm + 16 * mi + 4 * lg + r) * N + n0 + 16 * ci + lr] =
                    acc[mi][ci][r];
}

// ------------- V transpose per head: Vrow[bh][n][64] -> Vt[bh][64][n] ------
__global__ __launch_bounds__(256) void vtrans(const __bf16* __restrict__ Vrow,
                                              __bf16* __restrict__ Vt) {
    __shared__ __bf16 t[64][66];
    int bh = blockIdx.y, n0 = blockIdx.x * 64;
    int w = threadIdx.x >> 6, lane = threadIdx.x & 63;
#pragma unroll
    for (int i = 0; i < 16; ++i) {
        int nl = 16 * w + i;
        t[nl][lane] = Vrow[((size_t)bh * N_ + n0 + nl) * DH_ + lane];
    }
    __syncthreads();
#pragma unroll
    for (int i = 0; i < 16; ++i) {
        int d = 16 * w + i;
        Vt[(size_t)bh * DH_ * N_ + (size_t)d * N_ + n0 + lane] = t[lane][d];
    }
}

// ------- causal flash attention, split-KV, FIXED-MAX softmax ---------------
__global__ __launch_bounds__(256) void attn_kernel(const __bf16* __restrict__ Qh,
                                                   const __bf16* __restrict__ Kh,
                                                   const __bf16* __restrict__ Vt,
                                                   float* __restrict__ Opart,
                                                   float* __restrict__ lpart) {
    __shared__ __bf16 Ks[2][64 * 64];
    __shared__ __bf16 Vs[2][64 * 64];
    __shared__ __bf16 pl[4][16 * 64];   // per-wave, XOR-swizzled
    int bh  = blockIdx.x & 15;
    int sid = blockIdx.x >> 4;           // 0..79, heavy-first order
    int s, qt;
    if (sid < 32)      { s = 0; qt = 31 - sid; }
    else if (sid < 56) { s = 1; qt = 31 - (sid - 32); }
    else if (sid < 72) { s = 2; qt = 31 - (sid - 56); }
    else               { s = 3; qt = 31 - (sid - 72); }
    int jt0 = 8 * s;
    int jt1 = min(8 * s + 7, qt);
    int tid = threadIdx.x;
    int w = tid >> 6, lane = tid & 63;
    int lr = lane & 15, lg = lane >> 4;
    int qrow = qt * 64 + 16 * w;
    const __bf16* Qp = Qh + (size_t)bh * N_ * DH_;
    const __bf16* Kp = Kh + (size_t)bh * N_ * DH_;
    const __bf16* Vp = Vt + (size_t)bh * DH_ * N_;
    bf16x8 qf0 = *reinterpret_cast<const bf16x8*>(Qp + (size_t)(qrow + lr) * DH_ + 8 * lg);
    bf16x8 qf1 = *reinterpret_cast<const bf16x8*>(Qp + (size_t)(qrow + lr) * DH_ + 32 + 8 * lg);
    bf16x8 ones;
#pragma unroll
    for (int j = 0; j < 8; ++j) ones[j] = (__bf16)1.0f;
    f32x4 oacc[4];
    f32x4 oacc4 = f32x4{0.f, 0.f, 0.f, 0.f};   // ones-column: row sums (l)
#pragma unroll
    for (int c = 0; c < 4; ++c) oacc[c] = f32x4{0.f, 0.f, 0.f, 0.f};
    int srow = tid >> 3, sc = tid & 7;

    auto stage = [&](int buf, int jb) {
#pragma unroll
        for (int q = 0; q < 2; ++q) {
            int row = q * 32 + srow;
            int cs = sc ^ (row & 7);
            gld_lds16(Kp + (size_t)(jb + row) * DH_ + 8 * cs,
                      &Ks[buf][(size_t)row * 64 + sc * 8]);
            gld_lds16(Vp + (size_t)row * N_ + jb + 8 * cs,
                      &Vs[buf][(size_t)row * 64 + sc * 8]);
        }
    };

    stage(0, jt0 * 64);
    __syncthreads();
    int cur = 0;
    for (int jt = jt0; jt <= jt1; ++jt) {
        int jb = jt * 64;
        if (jt < jt1) stage(cur ^ 1, jb + 64);
        const __bf16* ks = &Ks[cur][0];
        const __bf16* vs = &Vs[cur][0];
        f32x4 sm[4];
#pragma unroll
        for (int ch = 0; ch < 4; ++ch) {
            int row = 16 * ch + lr;
            bf16x8 k0 = *reinterpret_cast<const bf16x8*>(&ks[row * 64 + 8 * (lg ^ (row & 7))]);
            bf16x8 k1 = *reinterpret_cast<const bf16x8*>(&ks[row * 64 + 8 * ((4 + lg) ^ (row & 7))]);
            f32x4 t = f32x4{0.f, 0.f, 0.f, 0.f};
            t = mfma16(qf0, k0, t);
            t = mfma16(qf1, k1, t);
            sm[ch] = t;
        }
        f32x4 p[4];
        bool diag = (jt == qt);
#pragma unroll
        for (int ch = 0; ch < 4; ++ch)
#pragma unroll
            for (int r = 0; r < 4; ++r) {
                float pv = exp2f(sm[ch][r] - MAXL2_);
                if (diag) {
                    int qi = qrow + 4 * lg + r;
                    int j  = jb + 16 * ch + lr;
                    if (j > qi) pv = 0.f;
                }
                p[ch][r] = pv;
            }
        __bf16* plw = &pl[w][0];
#pragma unroll
        for (int ch = 0; ch < 4; ++ch)
#pragma unroll
            for (int r = 0; r < 4; ++r) {
                int row = 4 * lg + r, col = 16 * ch + lr;
                plw[row * 64 + (((col >> 3) ^ (row & 7)) << 3) + (col & 7)] = (__bf16)p[ch][r];
            }
        bf16x8 pf0 = *reinterpret_cast<const bf16x8*>(&plw[lr * 64 + ((lg ^ (lr & 7)) << 3)]);
        bf16x8 pf1 = *reinterpret_cast<const bf16x8*>(&plw[lr * 64 + (((4 + lg) ^ (lr & 7)) << 3)]);
#pragma unroll
        for (int dc = 0; dc < 4; ++dc) {
            int row = 16 * dc + lr;
            bf16x8 v0 = *reinterpret_cast<const bf16x8*>(&vs[row * 64 + 8 * (lg ^ (row & 7))]);
            bf16x8 v1 = *reinterpret_cast<const bf16x8*>(&vs[row * 64 + 8 * ((4 + lg) ^ (row & 7))]);
            oacc[dc] = mfma16(pf0, v0, oacc[dc]);
            oacc[dc] = mfma16(pf1, v1, oacc[dc]);
        }
        oacc4 = mfma16(pf0, ones, oacc4);
        oacc4 = mfma16(pf1, ones, oacc4);
        __syncthreads();
        cur ^= 1;
    }
    int soff = 2048 * s - 256 * s * (s - 1);   // {0,2048,3584,4608}
#pragma unroll
    for (int r = 0; r < 4; ++r) {
        int n = qrow + 4 * lg + r;
        size_t ridx = (size_t)bh * SEGROWS_ + soff + (n - 512 * s);
#pragma unroll
        for (int dc = 0; dc < 4; ++dc)
            Opart[ridx * 64 + 16 * dc + lr] = oacc[dc][r];
        if (lr == 0) lpart[ridx] = oacc4[r];
    }
}

// ----------- combine partial segments -> normalized O (bf16) ---------------
__global__ __launch_bounds__(256) void combine_kernel(const float* __restrict__ Opart,
                                                      const float* __restrict__ lpart,
                                                      __bf16* __restrict__ Obp) {
    int gid = blockIdx.x * 4 + (threadIdx.x >> 6);   // q-row id 0..32767
    int lane = threadIdx.x & 63;
    int bh = gid >> 11, n = gid & 2047;
    int smax = n >> 9;
    float acc = 0.f, lsum = 0.f;
#pragma unroll
    for (int s = 0; s < 4; ++s)
        if (s <= smax) {
            int soff = 2048 * s - 256 * s * (s - 1);
            size_t ridx = (size_t)bh * SEGROWS_ + soff + (n - 512 * s);
            acc  += Opart[ridx * 64 + lane];
            lsum += lpart[ridx];
        }
    int b = bh >> 3, h = bh & 7;
    Obp[((size_t)(b * N_ + n)) * INNER_ + h * DH_ + lane] = (__bf16)(acc / lsum);
}

extern "C" void kernel_launch(void* const* d_in, const int* in_sizes, int n_in,
                              void* d_out, int out_size, void* d_ws, size_t ws_size,
                              hipStream_t stream) {
    const float* x    = (const float*)d_in[0];
    const float* lnw  = (const float*)d_in[1];
    const float* lnb  = (const float*)d_in[2];
    const float* wqkv = (const float*)d_in[3];
    const float* wout = (const float*)d_in[4];
    float* out = (float*)d_out;

    char* ws = (char*)d_ws;
    size_t off = 0;
    auto alloc = [&](size_t bytes) -> char* {
        char* p = ws + off;
        off += (bytes + 255) & ~(size_t)255;
        return p;
    };
    __bf16* xn    = (__bf16*)alloc((size_t)ROWS_ * DIM_ * 2);
    __bf16* wqkvT = (__bf16*)alloc((size_t)QKVN_ * DIM_ * 2);
    __bf16* woutT = (__bf16*)alloc((size_t)DIM_ * INNER_ * 2);
    __bf16* Qhp   = (__bf16*)alloc((size_t)B_ * H_ * N_ * DH_ * 2);
    __bf16* Khp   = (__bf16*)alloc((size_t)B_ * H_ * N_ * DH_ * 2);
    __bf16* Vrow  = (__bf16*)alloc((size_t)B_ * H_ * N_ * DH_ * 2);
    __bf16* Vtp   = (__bf16*)alloc((size_t)B_ * H_ * DH_ * N_ * 2);
    __bf16* Obp   = (__bf16*)alloc((size_t)ROWS_ * INNER_ * 2);
    float*  Opart = (float*)alloc((size_t)B_ * H_ * SEGROWS_ * DH_ * 4);
    float*  lbuf  = (float*)alloc((size_t)B_ * H_ * SEGROWS_ * 4);
    if (off > ws_size) return;

    transpose_both<<<512, 256, 0, stream>>>(wqkv, wout, wqkvT, woutT);
    ln_kernel<<<ROWS_, 256, 0, stream>>>(x, lnw, lnb, xn);
    gemm_qkv<<<dim3(QKVN_ / 128, ROWS_ / 128), 256, 0, stream>>>(xn, wqkvT, Qhp, Khp, Vrow);
    vtrans<<<dim3(N_ / 64, B_ * H_), 256, 0, stream>>>(Vrow, Vtp);
    attn_kernel<<<1280, 256, 0, stream>>>(Qhp, Khp, Vtp, Opart, lbuf);
    combine_kernel<<<(ROWS_ * H_) / 4, 256, 0, stream>>>(Opart, lbuf, Obp);
    gemm_out<<<dim3(DIM_ / 64, ROWS_ / 128), 256, 0, stream>>>(Obp, woutT, out);
}

// Round 6
// 153.163 us; speedup vs baseline: 2.4607x; 1.0894x over previous
//
#include <hip/hip_runtime.h>
#include <hip/hip_bf16.h>

typedef __attribute__((ext_vector_type(8))) __bf16 bf16x8;
typedef __attribute__((ext_vector_type(4))) __bf16 bf16x4;
typedef __attribute__((ext_vector_type(4))) float f32x4;

#define B_     2
#define N_     2048
#define DIM_   1024
#define INNER_ 512
#define H_     8
#define DH_    64
#define ROWS_  (B_ * N_)      // 4096
#define QKVN_  (3 * INNER_)   // 1536
#define SEGROWS_ 5120         // per-bh partial rows: 2048+1536+1024+512
#define QSCALE_ 11.5415603f   // 8 * log2(e): exp2-domain cosine scale
#define MAXL2_  11.5415603f   // fixed softmax max in exp2 domain

static __device__ __forceinline__ f32x4 mfma16(bf16x8 a, bf16x8 b, f32x4 c) {
    return __builtin_amdgcn_mfma_f32_16x16x32_bf16(a, b, c, 0, 0, 0);
}

static __device__ __forceinline__ void gld_lds16(const void* g, void* l) {
    __builtin_amdgcn_global_load_lds((const __attribute__((address_space(1))) void*)g,
                                     (__attribute__((address_space(3))) void*)l, 16, 0, 0);
}

// ---------------- LayerNorm: x fp32 [4096][1024] -> xn bf16 ----------------
__global__ __launch_bounds__(256) void ln_kernel(const float* __restrict__ x,
                                                 const float* __restrict__ w,
                                                 const float* __restrict__ bb,
                                                 __bf16* __restrict__ xn) {
    int row = blockIdx.x;
    int tid = threadIdx.x;
    const float* xr = x + (size_t)row * DIM_;
    f32x4 xv = *reinterpret_cast<const f32x4*>(xr + tid * 4);
    float s  = xv.x + xv.y + xv.z + xv.w;
    float sq = xv.x * xv.x + xv.y * xv.y + xv.z * xv.z + xv.w * xv.w;
#pragma unroll
    for (int m = 1; m < 64; m <<= 1) {
        s  += __shfl_xor(s, m);
        sq += __shfl_xor(sq, m);
    }
    __shared__ float red[2][4];
    int wid = tid >> 6, lane = tid & 63;
    if (lane == 0) { red[0][wid] = s; red[1][wid] = sq; }
    __syncthreads();
    s  = red[0][0] + red[0][1] + red[0][2] + red[0][3];
    sq = red[1][0] + red[1][1] + red[1][2] + red[1][3];
    float mu   = s * (1.0f / DIM_);
    float var  = sq * (1.0f / DIM_) - mu * mu;
    float rstd = rsqrtf(var + 1e-5f);
    f32x4 wv = *reinterpret_cast<const f32x4*>(w  + tid * 4);
    f32x4 bv = *reinterpret_cast<const f32x4*>(bb + tid * 4);
    bf16x4 o;
#pragma unroll
    for (int j = 0; j < 4; ++j) o[j] = (__bf16)((xv[j] - mu) * rstd * wv[j] + bv[j]);
    *reinterpret_cast<bf16x4*>(xn + (size_t)row * DIM_ + tid * 4) = o;
}

// ---- both weight transposes in ONE launch: fp32 [K][N] -> bf16 [N][K] -----
__global__ __launch_bounds__(256) void transpose_both(const float* __restrict__ wqkv,
                                                      const float* __restrict__ wout,
                                                      __bf16* __restrict__ wqkvT,
                                                      __bf16* __restrict__ woutT) {
    __shared__ float t[64][65];
    int bid = blockIdx.x;
    const float* in; __bf16* out; int K, N, bx, by;
    if (bid < 384) { in = wqkv; out = wqkvT; K = DIM_;   N = QKVN_; bx = bid % 24; by = bid / 24; }
    else { bid -= 384; in = wout; out = woutT; K = INNER_; N = DIM_;  bx = bid % 16; by = bid / 16; }
    int n0 = bx * 64, k0 = by * 64;
    int w = threadIdx.x >> 6, lane = threadIdx.x & 63;
#pragma unroll
    for (int i = 0; i < 16; ++i) {
        int k = 16 * w + i;
        t[k][lane] = in[(size_t)(k0 + k) * N + n0 + lane];
    }
    __syncthreads();
#pragma unroll
    for (int i = 0; i < 16; ++i) {
        int n = 16 * w + i;
        out[(size_t)(n0 + n) * K + k0 + lane] = (__bf16)t[lane][n];
    }
}

// ------ fused QKV GEMM: 128x64 tile, BK=64, conflict-free 8-way swizzle ----
// grid 768 (XCD-chunked); wave = 32(M) x 64(N); l2norm epilogue, head-major.
__global__ __launch_bounds__(256) void gemm_qkv(const __bf16* __restrict__ A,
                                                const __bf16* __restrict__ Bt,
                                                __bf16* __restrict__ Qh,
                                                __bf16* __restrict__ Kh,
                                                __bf16* __restrict__ Vrow) {
    const int K = DIM_;
    __shared__ __bf16 As[2][128 * 64];
    __shared__ __bf16 Bs[2][64 * 64];
    int id = blockIdx.x;
    int nid = (id & 7) * 96 + (id >> 3);     // XCD-chunked: 96 consecutive/XCD
    int bx = nid % 24, by = nid / 24;
    int tid = threadIdx.x;
    int w = tid >> 6, lane = tid & 63;
    int lr = lane & 15, lg = lane >> 4;
    int m0 = by * 128, n0 = bx * 64;
    int sr = tid >> 3;      // 0..31
    int sc8 = tid & 7;      // 16B chunk slot 0..7
    const __bf16* Ab = A  + (size_t)m0 * K;
    const __bf16* Bb = Bt + (size_t)n0 * K;
    f32x4 acc[2][4];
#pragma unroll
    for (int mi = 0; mi < 2; ++mi)
#pragma unroll
        for (int ci = 0; ci < 4; ++ci) acc[mi][ci] = f32x4{0.f, 0.f, 0.f, 0.f};

    auto stage = [&](int buf, int k0) {
#pragma unroll
        for (int i = 0; i < 4; ++i) {
            int r = sr + i * 32;
            int cs = sc8 ^ (r & 7);          // pre-swizzled source, linear dest
            gld_lds16(Ab + (size_t)r * K + k0 + 8 * cs, &As[buf][r * 64 + sc8 * 8]);
        }
#pragma unroll
        for (int i = 0; i < 2; ++i) {
            int r = sr + i * 32;
            int cs = sc8 ^ (r & 7);
            gld_lds16(Bb + (size_t)r * K + k0 + 8 * cs, &Bs[buf][r * 64 + sc8 * 8]);
        }
    };

    stage(0, 0);
    __syncthreads();
    int cur = 0;
    for (int k0 = 0; k0 < K; k0 += 64) {
        if (k0 + 64 < K) stage(cur ^ 1, k0 + 64);
        bf16x8 af[2][2], bfr[2][4];
#pragma unroll
        for (int kk = 0; kk < 2; ++kk) {
#pragma unroll
            for (int mi = 0; mi < 2; ++mi) {
                int r = w * 32 + 16 * mi + lr;
                af[kk][mi] = *reinterpret_cast<const bf16x8*>(
                    &As[cur][r * 64 + 8 * ((kk * 4 + lg) ^ (r & 7))]);
            }
#pragma unroll
            for (int ci = 0; ci < 4; ++ci) {
                int r = 16 * ci + lr;
                bfr[kk][ci] = *reinterpret_cast<const bf16x8*>(
                    &Bs[cur][r * 64 + 8 * ((kk * 4 + lg) ^ (r & 7))]);
            }
        }
#pragma unroll
        for (int kk = 0; kk < 2; ++kk)
#pragma unroll
            for (int mi = 0; mi < 2; ++mi)
#pragma unroll
                for (int ci = 0; ci < 4; ++ci)
                    acc[mi][ci] = mfma16(af[kk][mi], bfr[kk][ci], acc[mi][ci]);
        __syncthreads();
        cur ^= 1;
    }
    int u = bx;                        // 0..23: Q heads 0-7, K heads 8-15, V 16-23
    bool isV = (u >= 16);
    float smul = (u < 8) ? QSCALE_ : 1.0f;
    __bf16* base;
    if (u < 8)       base = Qh   + (size_t)u * N_ * DH_;
    else if (u < 16) base = Kh   + (size_t)(u - 8) * N_ * DH_;
    else             base = Vrow + (size_t)(u - 16) * N_ * DH_;
#pragma unroll
    for (int mi = 0; mi < 2; ++mi)
#pragma unroll
        for (int r = 0; r < 4; ++r) {
            int grow = m0 + w * 32 + 16 * mi + 4 * lg + r;
            int b = grow >> 11, n = grow & 2047;
            float sc2 = 1.0f;
            if (!isV) {
                float t = 0.f;
#pragma unroll
                for (int ci = 0; ci < 4; ++ci) t += acc[mi][ci][r] * acc[mi][ci][r];
#pragma unroll
                for (int m = 1; m < 16; m <<= 1) t += __shfl_xor(t, m);
                sc2 = rsqrtf(t + 1e-12f) * smul;
            }
            __bf16* dst = base + ((size_t)b * H_ * N_ + n) * DH_;
#pragma unroll
            for (int ci = 0; ci < 4; ++ci)
                dst[16 * ci + lr] = (__bf16)(acc[mi][ci][r] * sc2);
        }
}

// ---- out-proj GEMM: 64x64 tile, BK=64, 1024 blocks (XCD-chunked) ----------
__global__ __launch_bounds__(256) void gemm_out(const __bf16* __restrict__ A,
                                                const __bf16* __restrict__ Bt,
                                                float* __restrict__ C) {
    const int K = INNER_, N = DIM_;
    __shared__ __bf16 As[2][64 * 64];
    __shared__ __bf16 Bs[2][64 * 64];
    int id = blockIdx.x;
    int nid = (id & 7) * 128 + (id >> 3);
    int bx = nid % 16, by = nid / 16;
    int tid = threadIdx.x;
    int w = tid >> 6, lane = tid & 63;
    int lr = lane & 15, lg = lane >> 4;
    int m0 = by * 64, n0 = bx * 64;
    int sr = tid >> 3, sc8 = tid & 7;
    const __bf16* Ab = A  + (size_t)m0 * K;
    const __bf16* Bb = Bt + (size_t)n0 * K;
    f32x4 acc[4];
#pragma unroll
    for (int ci = 0; ci < 4; ++ci) acc[ci] = f32x4{0.f, 0.f, 0.f, 0.f};

    auto stage = [&](int buf, int k0) {
#pragma unroll
        for (int i = 0; i < 2; ++i) {
            int r = sr + i * 32;
            int cs = sc8 ^ (r & 7);
            gld_lds16(Ab + (size_t)r * K + k0 + 8 * cs, &As[buf][r * 64 + sc8 * 8]);
            gld_lds16(Bb + (size_t)r * K + k0 + 8 * cs, &Bs[buf][r * 64 + sc8 * 8]);
        }
    };

    stage(0, 0);
    __syncthreads();
    int cur = 0;
    for (int k0 = 0; k0 < K; k0 += 64) {
        if (k0 + 64 < K) stage(cur ^ 1, k0 + 64);
        bf16x8 af[2], bfr[2][4];
#pragma unroll
        for (int kk = 0; kk < 2; ++kk) {
            int r = w * 16 + lr;
            af[kk] = *reinterpret_cast<const bf16x8*>(
                &As[cur][r * 64 + 8 * ((kk * 4 + lg) ^ (r & 7))]);
#pragma unroll
            for (int ci = 0; ci < 4; ++ci) {
                int rb = 16 * ci + lr;
                bfr[kk][ci] = *reinterpret_cast<const bf16x8*>(
                    &Bs[cur][rb * 64 + 8 * ((kk * 4 + lg) ^ (rb & 7))]);
            }
        }
#pragma unroll
        for (int kk = 0; kk < 2; ++kk)
#pragma unroll
            for (int ci = 0; ci < 4; ++ci)
                acc[ci] = mfma16(af[kk], bfr[kk][ci], acc[ci]);
        __syncthreads();
        cur ^= 1;
    }
#pragma unroll
    for (int ci = 0; ci < 4; ++ci)
#pragma unroll
        for (int r = 0; r < 4; ++r)
            C[(size_t)(m0 + w * 16 + 4 * lg + r) * N + n0 + 16 * ci + lr] = acc[ci][r];
}

// ------------- V transpose per head: Vrow[bh][n][64] -> Vt[bh][64][n] ------
__global__ __launch_bounds__(256) void vtrans(const __bf16* __restrict__ Vrow,
                                              __bf16* __restrict__ Vt) {
    __shared__ __bf16 t[64][66];
    int bh = blockIdx.y, n0 = blockIdx.x * 64;
    int w = threadIdx.x >> 6, lane = threadIdx.x & 63;
#pragma unroll
    for (int i = 0; i < 16; ++i) {
        int nl = 16 * w + i;
        t[nl][lane] = Vrow[((size_t)bh * N_ + n0 + nl) * DH_ + lane];
    }
    __syncthreads();
#pragma unroll
    for (int i = 0; i < 16; ++i) {
        int d = 16 * w + i;
        Vt[(size_t)bh * DH_ * N_ + (size_t)d * N_ + n0 + lane] = t[lane][d];
    }
}

// ------- causal flash attention, split-KV, FIXED-MAX softmax ---------------
__global__ __launch_bounds__(256) void attn_kernel(const __bf16* __restrict__ Qh,
                                                   const __bf16* __restrict__ Kh,
                                                   const __bf16* __restrict__ Vt,
                                                   float* __restrict__ Opart,
                                                   float* __restrict__ lpart) {
    __shared__ __bf16 Ks[2][64 * 64];
    __shared__ __bf16 Vs[2][64 * 64];
    __shared__ __bf16 pl[4][16 * 64];   // per-wave, XOR-swizzled
    int bh  = blockIdx.x & 15;
    int sid = blockIdx.x >> 4;           // 0..79, heavy-first order
    int s, qt;
    if (sid < 32)      { s = 0; qt = 31 - sid; }
    else if (sid < 56) { s = 1; qt = 31 - (sid - 32); }
    else if (sid < 72) { s = 2; qt = 31 - (sid - 56); }
    else               { s = 3; qt = 31 - (sid - 72); }
    int jt0 = 8 * s;
    int jt1 = min(8 * s + 7, qt);
    int tid = threadIdx.x;
    int w = tid >> 6, lane = tid & 63;
    int lr = lane & 15, lg = lane >> 4;
    int qrow = qt * 64 + 16 * w;
    const __bf16* Qp = Qh + (size_t)bh * N_ * DH_;
    const __bf16* Kp = Kh + (size_t)bh * N_ * DH_;
    const __bf16* Vp = Vt + (size_t)bh * DH_ * N_;
    bf16x8 qf0 = *reinterpret_cast<const bf16x8*>(Qp + (size_t)(qrow + lr) * DH_ + 8 * lg);
    bf16x8 qf1 = *reinterpret_cast<const bf16x8*>(Qp + (size_t)(qrow + lr) * DH_ + 32 + 8 * lg);
    bf16x8 ones;
#pragma unroll
    for (int j = 0; j < 8; ++j) ones[j] = (__bf16)1.0f;
    f32x4 oacc[4];
    f32x4 oacc4 = f32x4{0.f, 0.f, 0.f, 0.f};   // ones-column: row sums (l)
#pragma unroll
    for (int c = 0; c < 4; ++c) oacc[c] = f32x4{0.f, 0.f, 0.f, 0.f};
    int srow = tid >> 3, sc = tid & 7;

    auto stage = [&](int buf, int jb) {
#pragma unroll
        for (int q = 0; q < 2; ++q) {
            int row = q * 32 + srow;
            int cs = sc ^ (row & 7);
            gld_lds16(Kp + (size_t)(jb + row) * DH_ + 8 * cs,
                      &Ks[buf][(size_t)row * 64 + sc * 8]);
            gld_lds16(Vp + (size_t)row * N_ + jb + 8 * cs,
                      &Vs[buf][(size_t)row * 64 + sc * 8]);
        }
    };

    stage(0, jt0 * 64);
    __syncthreads();
    int cur = 0;
    for (int jt = jt0; jt <= jt1; ++jt) {
        int jb = jt * 64;
        if (jt < jt1) stage(cur ^ 1, jb + 64);
        const __bf16* ks = &Ks[cur][0];
        const __bf16* vs = &Vs[cur][0];
        f32x4 sm[4];
#pragma unroll
        for (int ch = 0; ch < 4; ++ch) {
            int row = 16 * ch + lr;
            bf16x8 k0 = *reinterpret_cast<const bf16x8*>(&ks[row * 64 + 8 * (lg ^ (row & 7))]);
            bf16x8 k1 = *reinterpret_cast<const bf16x8*>(&ks[row * 64 + 8 * ((4 + lg) ^ (row & 7))]);
            f32x4 t = f32x4{0.f, 0.f, 0.f, 0.f};
            t = mfma16(qf0, k0, t);
            t = mfma16(qf1, k1, t);
            sm[ch] = t;
        }
        f32x4 p[4];
        bool diag = (jt == qt);
#pragma unroll
        for (int ch = 0; ch < 4; ++ch)
#pragma unroll
            for (int r = 0; r < 4; ++r) {
                float pv = exp2f(sm[ch][r] - MAXL2_);
                if (diag) {
                    int qi = qrow + 4 * lg + r;
                    int j  = jb + 16 * ch + lr;
                    if (j > qi) pv = 0.f;
                }
                p[ch][r] = pv;
            }
        __bf16* plw = &pl[w][0];
#pragma unroll
        for (int ch = 0; ch < 4; ++ch)
#pragma unroll
            for (int r = 0; r < 4; ++r) {
                int row = 4 * lg + r, col = 16 * ch + lr;
                plw[row * 64 + (((col >> 3) ^ (row & 7)) << 3) + (col & 7)] = (__bf16)p[ch][r];
            }
        bf16x8 pf0 = *reinterpret_cast<const bf16x8*>(&plw[lr * 64 + ((lg ^ (lr & 7)) << 3)]);
        bf16x8 pf1 = *reinterpret_cast<const bf16x8*>(&plw[lr * 64 + (((4 + lg) ^ (lr & 7)) << 3)]);
#pragma unroll
        for (int dc = 0; dc < 4; ++dc) {
            int row = 16 * dc + lr;
            bf16x8 v0 = *reinterpret_cast<const bf16x8*>(&vs[row * 64 + 8 * (lg ^ (row & 7))]);
            bf16x8 v1 = *reinterpret_cast<const bf16x8*>(&vs[row * 64 + 8 * ((4 + lg) ^ (row & 7))]);
            oacc[dc] = mfma16(pf0, v0, oacc[dc]);
            oacc[dc] = mfma16(pf1, v1, oacc[dc]);
        }
        oacc4 = mfma16(pf0, ones, oacc4);
        oacc4 = mfma16(pf1, ones, oacc4);
        __syncthreads();
        cur ^= 1;
    }
    int soff = 2048 * s - 256 * s * (s - 1);   // {0,2048,3584,4608}
#pragma unroll
    for (int r = 0; r < 4; ++r) {
        int n = qrow + 4 * lg + r;
        size_t ridx = (size_t)bh * SEGROWS_ + soff + (n - 512 * s);
#pragma unroll
        for (int dc = 0; dc < 4; ++dc)
            Opart[ridx * 64 + 16 * dc + lr] = oacc[dc][r];
        if (lr == 0) lpart[ridx] = oacc4[r];
    }
}

// ----------- combine partial segments -> normalized O (bf16) ---------------
__global__ __launch_bounds__(256) void combine_kernel(const float* __restrict__ Opart,
                                                      const float* __restrict__ lpart,
                                                      __bf16* __restrict__ Obp) {
    int gid = blockIdx.x * 4 + (threadIdx.x >> 6);   // q-row id 0..32767
    int lane = threadIdx.x & 63;
    int bh = gid >> 11, n = gid & 2047;
    int smax = n >> 9;
    float acc = 0.f, lsum = 0.f;
#pragma unroll
    for (int s = 0; s < 4; ++s)
        if (s <= smax) {
            int soff = 2048 * s - 256 * s * (s - 1);
            size_t ridx = (size_t)bh * SEGROWS_ + soff + (n - 512 * s);
            acc  += Opart[ridx * 64 + lane];
            lsum += lpart[ridx];
        }
    int b = bh >> 3, h = bh & 7;
    Obp[((size_t)(b * N_ + n)) * INNER_ + h * DH_ + lane] = (__bf16)(acc / lsum);
}

extern "C" void kernel_launch(void* const* d_in, const int* in_sizes, int n_in,
                              void* d_out, int out_size, void* d_ws, size_t ws_size,
                              hipStream_t stream) {
    const float* x    = (const float*)d_in[0];
    const float* lnw  = (const float*)d_in[1];
    const float* lnb  = (const float*)d_in[2];
    const float* wqkv = (const float*)d_in[3];
    const float* wout = (const float*)d_in[4];
    float* out = (float*)d_out;

    char* ws = (char*)d_ws;
    size_t off = 0;
    auto alloc = [&](size_t bytes) -> char* {
        char* p = ws + off;
        off += (bytes + 255) & ~(size_t)255;
        return p;
    };
    __bf16* xn    = (__bf16*)alloc((size_t)ROWS_ * DIM_ * 2);
    __bf16* wqkvT = (__bf16*)alloc((size_t)QKVN_ * DIM_ * 2);
    __bf16* woutT = (__bf16*)alloc((size_t)DIM_ * INNER_ * 2);
    __bf16* Qhp   = (__bf16*)alloc((size_t)B_ * H_ * N_ * DH_ * 2);
    __bf16* Khp   = (__bf16*)alloc((size_t)B_ * H_ * N_ * DH_ * 2);
    __bf16* Vrow  = (__bf16*)alloc((size_t)B_ * H_ * N_ * DH_ * 2);
    __bf16* Vtp   = (__bf16*)alloc((size_t)B_ * H_ * DH_ * N_ * 2);
    __bf16* Obp   = (__bf16*)alloc((size_t)ROWS_ * INNER_ * 2);
    float*  Opart = (float*)alloc((size_t)B_ * H_ * SEGROWS_ * DH_ * 4);
    float*  lbuf  = (float*)alloc((size_t)B_ * H_ * SEGROWS_ * 4);
    if (off > ws_size) return;

    transpose_both<<<512, 256, 0, stream>>>(wqkv, wout, wqkvT, woutT);
    ln_kernel<<<ROWS_, 256, 0, stream>>>(x, lnw, lnb, xn);
    gemm_qkv<<<768, 256, 0, stream>>>(xn, wqkvT, Qhp, Khp, Vrow);
    vtrans<<<dim3(N_ / 64, B_ * H_), 256, 0, stream>>>(Vrow, Vtp);
    attn_kernel<<<1280, 256, 0, stream>>>(Qhp, Khp, Vtp, Opart, lbuf);
    combine_kernel<<<(ROWS_ * H_) / 4, 256, 0, stream>>>(Opart, lbuf, Obp);
    gemm_out<<<1024, 256, 0, stream>>>(Obp, woutT, out);
}